// Round 2
// baseline (24480.315 us; speedup 1.0000x reference)
//
#include <hip/hip_runtime.h>
#include <math.h>

// Problem constants (TransformerController)
#define B_  32
#define S_  512
#define T_  180
#define D_  512
#define F_  2048
#define L_  6
#define H_  8
#define DH_ 64

// ---------------------------------------------------------------------------
// Embedding kernels (projection + bias + sinusoidal positional encoding)
// ---------------------------------------------------------------------------
__device__ __forceinline__ float pos_enc(int pos, int c) {
    int i2 = c & ~1;
    float div = expf(-(float)i2 * (9.210340371976184f / 512.0f)); // ln(1e4)
    float arg = (float)pos * div;
    return (c & 1) ? cosf(arg) : sinf(arg);
}

__global__ __launch_bounds__(256) void embed_src_kernel(
    const float* __restrict__ x, const float* __restrict__ w,
    const float* __restrict__ b, float* __restrict__ h)
{
    int idx = blockIdx.x * 256 + threadIdx.x;
    if (idx >= B_ * S_ * D_) return;
    int c  = idx & (D_ - 1);
    int bs = idx >> 9;            // b*S + s  (D = 512)
    int s  = bs & (S_ - 1);       // S = 512
    float x0 = x[bs * 2 + 0];
    float x1 = x[bs * 2 + 1];
    h[idx] = x0 * w[c] + x1 * w[D_ + c] + b[c] + pos_enc(s, c);
}

__global__ __launch_bounds__(256) void embed_tgt_kernel(
    const float* __restrict__ y, const float* __restrict__ w,
    const float* __restrict__ b, float* __restrict__ d)
{
    int idx = blockIdx.x * 256 + threadIdx.x;
    if (idx >= B_ * T_ * D_) return;
    int c  = idx & (D_ - 1);
    int bt = idx >> 9;            // b*T + t
    int t  = bt % T_;
    int bb = bt / T_;
    float tv = (t == 0) ? 0.0f : y[bb * T_ + (t - 1)];  // [0, y[:, :-1]]
    d[idx] = tv * w[c] + b[c] + pos_enc(t, c);
}

// ---------------------------------------------------------------------------
// Tiled fp32 GEMM: C[M,N] = act(A[M,K] @ W[K,N] + bias[N]), act = relu or id.
// 64x64 tile, BK=16, 256 threads, 4x4 per thread. M,N mult of 64; K mult 16.
// ---------------------------------------------------------------------------
__global__ __launch_bounds__(256) void gemm_kernel(
    const float* __restrict__ A, const float* __restrict__ W,
    const float* __restrict__ bias, float* __restrict__ C,
    int M, int N, int K, int relu)
{
    __shared__ __align__(16) float As[16][68];
    __shared__ __align__(16) float Ws[16][68];

    int tid = threadIdx.x;
    int tx = tid & 15, ty = tid >> 4;
    int m0 = blockIdx.y << 6, n0 = blockIdx.x << 6;

    int la_r = tid >> 4;    // A-load row group, col = la_c
    int la_c = tid & 15;
    int lw_r = tid >> 6;    // W-load row 0..3 (+4*i), col = lw_c
    int lw_c = tid & 63;

    float acc[4][4] = {{0.f}};

    for (int k0 = 0; k0 < K; k0 += 16) {
#pragma unroll
        for (int i = 0; i < 4; ++i)
            As[la_c][la_r + 16 * i] =
                A[(size_t)(m0 + la_r + 16 * i) * K + k0 + la_c];
#pragma unroll
        for (int i = 0; i < 4; ++i)
            Ws[lw_r + 4 * i][lw_c] =
                W[(size_t)(k0 + lw_r + 4 * i) * N + n0 + lw_c];
        __syncthreads();

#pragma unroll
        for (int kk = 0; kk < 16; ++kk) {
            float4 a4 = *(const float4*)&As[kk][ty * 4];
            float4 w4 = *(const float4*)&Ws[kk][tx * 4];
            float av[4] = {a4.x, a4.y, a4.z, a4.w};
            float wv[4] = {w4.x, w4.y, w4.z, w4.w};
#pragma unroll
            for (int i = 0; i < 4; ++i)
#pragma unroll
                for (int j = 0; j < 4; ++j)
                    acc[i][j] = fmaf(av[i], wv[j], acc[i][j]);
        }
        __syncthreads();
    }

    float bv[4];
#pragma unroll
    for (int j = 0; j < 4; ++j) bv[j] = bias[n0 + tx * 4 + j];
#pragma unroll
    for (int i = 0; i < 4; ++i) {
        size_t row = (size_t)(m0 + ty * 4 + i);
        float v0 = acc[i][0] + bv[0];
        float v1 = acc[i][1] + bv[1];
        float v2 = acc[i][2] + bv[2];
        float v3 = acc[i][3] + bv[3];
        if (relu) {
            v0 = fmaxf(v0, 0.f); v1 = fmaxf(v1, 0.f);
            v2 = fmaxf(v2, 0.f); v3 = fmaxf(v3, 0.f);
        }
        *(float4*)&C[row * N + n0 + tx * 4] = make_float4(v0, v1, v2, v3);
    }
}

// ---------------------------------------------------------------------------
// Flash-style attention, IN-PLACE capable (O may alias Q: each block reads its
// Q rows into LDS before any store, and writes only the (rows x head-chans)
// slice that no other block reads). No __restrict__ on Q/O.
// One block = (b, h, 16-query tile); 64-key tiles, online softmax.
// ---------------------------------------------------------------------------
#define QB 16
#define KB 64

__global__ __launch_bounds__(256) void attn_kernel(
    const float* Q, const float* __restrict__ K,
    const float* __restrict__ V, float* O,
    int Sq, int Sk, int causal)
{
    __shared__ __align__(16) float Qs[QB][68];
    __shared__ __align__(16) float Ks[KB][68];
    __shared__ __align__(16) float Vs[KB][68];
    __shared__ float Ps[QB][65];
    __shared__ float m_s[QB], l_s[QB], mnew_s[QB], alpha_s[QB];

    int tid = threadIdx.x;
    int qi = tid >> 4;     // 0..15 query within tile
    int ci = tid & 15;     // 0..15 channel group (4 ch each)
    int q0 = blockIdx.x * QB;
    int hh = blockIdx.y;
    int bb = blockIdx.z;

    const float* Qb = Q + (size_t)bb * Sq * D_ + hh * DH_;
    const float* Kb = K + (size_t)bb * Sk * D_ + hh * DH_;
    const float* Vb = V + (size_t)bb * Sk * D_ + hh * DH_;

    for (int idx = tid; idx < QB * DH_; idx += 256) {
        int r = idx >> 6, c = idx & 63;
        int qg = q0 + r;
        Qs[r][c] = (qg < Sq) ? Qb[(size_t)qg * D_ + c] : 0.0f;
    }
    if (tid < QB) { m_s[tid] = -1e30f; l_s[tid] = 0.0f; }
    float acc0 = 0.f, acc1 = 0.f, acc2 = 0.f, acc3 = 0.f;
    __syncthreads();

    int kend = causal ? ((Sk < q0 + QB) ? Sk : (q0 + QB)) : Sk;
    for (int k0 = 0; k0 < kend; k0 += KB) {
        for (int idx = tid; idx < KB * DH_; idx += 256) {
            int r = idx >> 6, c = idx & 63;
            int kg = k0 + r;
            if (kg < Sk) {
                Ks[r][c] = Kb[(size_t)kg * D_ + c];
                Vs[r][c] = Vb[(size_t)kg * D_ + c];
            } else {
                Ks[r][c] = 0.0f;
                Vs[r][c] = 0.0f;
            }
        }
        __syncthreads();

        float s0 = 0.f, s1 = 0.f, s2 = 0.f, s3 = 0.f;
#pragma unroll
        for (int dc = 0; dc < DH_; dc += 4) {
            float4 q4 = *(const float4*)&Qs[qi][dc];
            float4 k0v = *(const float4*)&Ks[ci][dc];
            float4 k1v = *(const float4*)&Ks[ci + 16][dc];
            float4 k2v = *(const float4*)&Ks[ci + 32][dc];
            float4 k3v = *(const float4*)&Ks[ci + 48][dc];
            s0 += q4.x * k0v.x + q4.y * k0v.y + q4.z * k0v.z + q4.w * k0v.w;
            s1 += q4.x * k1v.x + q4.y * k1v.y + q4.z * k1v.z + q4.w * k1v.w;
            s2 += q4.x * k2v.x + q4.y * k2v.y + q4.z * k2v.z + q4.w * k2v.w;
            s3 += q4.x * k3v.x + q4.y * k3v.y + q4.z * k3v.z + q4.w * k3v.w;
        }
        int qg = q0 + qi;
        {
            int kg;
            kg = k0 + ci;
            Ps[qi][ci]      = (kg >= Sk || (causal && kg > qg)) ? -1e9f : s0 * 0.125f;
            kg = k0 + ci + 16;
            Ps[qi][ci + 16] = (kg >= Sk || (causal && kg > qg)) ? -1e9f : s1 * 0.125f;
            kg = k0 + ci + 32;
            Ps[qi][ci + 32] = (kg >= Sk || (causal && kg > qg)) ? -1e9f : s2 * 0.125f;
            kg = k0 + ci + 48;
            Ps[qi][ci + 48] = (kg >= Sk || (causal && kg > qg)) ? -1e9f : s3 * 0.125f;
        }
        __syncthreads();

        if (ci == 0) {
            float mx = m_s[qi];
#pragma unroll
            for (int j = 0; j < KB; ++j) mx = fmaxf(mx, Ps[qi][j]);
            mnew_s[qi] = mx;
            alpha_s[qi] = expf(m_s[qi] - mx);
        }
        __syncthreads();

        float mn = mnew_s[qi];
        Ps[qi][ci]      = expf(Ps[qi][ci]      - mn);
        Ps[qi][ci + 16] = expf(Ps[qi][ci + 16] - mn);
        Ps[qi][ci + 32] = expf(Ps[qi][ci + 32] - mn);
        Ps[qi][ci + 48] = expf(Ps[qi][ci + 48] - mn);
        __syncthreads();

        if (ci == 0) {
            float sum = 0.f;
#pragma unroll
            for (int j = 0; j < KB; ++j) sum += Ps[qi][j];
            l_s[qi] = l_s[qi] * alpha_s[qi] + sum;
            m_s[qi] = mnew_s[qi];
        }
        float al = alpha_s[qi];
        acc0 *= al; acc1 *= al; acc2 *= al; acc3 *= al;
#pragma unroll
        for (int kj = 0; kj < KB; ++kj) {
            float p = Ps[qi][kj];
            float4 v4 = *(const float4*)&Vs[kj][ci * 4];
            acc0 = fmaf(p, v4.x, acc0);
            acc1 = fmaf(p, v4.y, acc1);
            acc2 = fmaf(p, v4.z, acc2);
            acc3 = fmaf(p, v4.w, acc3);
        }
        __syncthreads();
    }

    int qg = q0 + qi;
    if (qg < Sq) {
        float inv = 1.0f / l_s[qi];
        float* Op = O + (size_t)bb * Sq * D_ + (size_t)qg * D_ + hh * DH_ + ci * 4;
        Op[0] = acc0 * inv; Op[1] = acc1 * inv;
        Op[2] = acc2 * inv; Op[3] = acc3 * inv;
    }
}

// ---------------------------------------------------------------------------
// h[row,:] = LN(h[row,:] + delta[row,:]) * scale + bias   (D=512, 128 thr)
// ---------------------------------------------------------------------------
__global__ __launch_bounds__(128) void add_ln_kernel(
    float* __restrict__ h, const float* __restrict__ delta,
    const float* __restrict__ scale, const float* __restrict__ bias)
{
    __shared__ float red[128];
    int row = blockIdx.x, tid = threadIdx.x;
    size_t base = (size_t)row * D_ + tid * 4;
    float4 hv = *(const float4*)&h[base];
    float4 dv = *(const float4*)&delta[base];
    float v0 = hv.x + dv.x, v1 = hv.y + dv.y, v2 = hv.z + dv.z, v3 = hv.w + dv.w;

    red[tid] = v0 + v1 + v2 + v3;
    __syncthreads();
    for (int off = 64; off > 0; off >>= 1) {
        if (tid < off) red[tid] += red[tid + off];
        __syncthreads();
    }
    float mu = red[0] * (1.0f / 512.0f);
    __syncthreads();

    float d0 = v0 - mu, d1 = v1 - mu, d2 = v2 - mu, d3 = v3 - mu;
    red[tid] = d0 * d0 + d1 * d1 + d2 * d2 + d3 * d3;
    __syncthreads();
    for (int off = 64; off > 0; off >>= 1) {
        if (tid < off) red[tid] += red[tid + off];
        __syncthreads();
    }
    float var = red[0] * (1.0f / 512.0f);
    float rs = rsqrtf(var + 1e-5f);

    int c = tid * 4;
    float4 sc = *(const float4*)&scale[c];
    float4 bi = *(const float4*)&bias[c];
    *(float4*)&h[base] = make_float4(
        d0 * rs * sc.x + bi.x, d1 * rs * sc.y + bi.y,
        d2 * rs * sc.z + bi.z, d3 * rs * sc.w + bi.w);
}

// ---------------------------------------------------------------------------
// out[row] = d[row,:] . w[:] + b   (one wave per row)
// ---------------------------------------------------------------------------
__global__ __launch_bounds__(64) void out_proj_kernel(
    const float* __restrict__ d, const float* __restrict__ w,
    const float* __restrict__ b, float* __restrict__ out)
{
    int row = blockIdx.x, lane = threadIdx.x;
    float s = 0.f;
    for (int c = lane; c < D_; c += 64) s += d[(size_t)row * D_ + c] * w[c];
#pragma unroll
    for (int off = 32; off > 0; off >>= 1) s += __shfl_down(s, off);
    if (lane == 0) out[row] = s + b[0];
}

// ---------------------------------------------------------------------------
// Host orchestration
// ---------------------------------------------------------------------------
extern "C" void kernel_launch(void* const* d_in, const int* in_sizes, int n_in,
                              void* d_out, int out_size, void* d_ws, size_t ws_size,
                              hipStream_t stream)
{
    const float* x          = (const float*)d_in[0];
    const float* y          = (const float*)d_in[1];
    const float* src_w      = (const float*)d_in[2];
    const float* src_b      = (const float*)d_in[3];
    const float* tgt_w      = (const float*)d_in[4];
    const float* tgt_b      = (const float*)d_in[5];
    const float* enc_attn_w = (const float*)d_in[6];
    const float* enc_attn_b = (const float*)d_in[7];
    const float* enc_ffn_w1 = (const float*)d_in[8];
    const float* enc_ffn_b1 = (const float*)d_in[9];
    const float* enc_ffn_w2 = (const float*)d_in[10];
    const float* enc_ffn_b2 = (const float*)d_in[11];
    const float* enc_ln_s   = (const float*)d_in[12];
    const float* enc_ln_b   = (const float*)d_in[13];
    const float* dec_self_w = (const float*)d_in[14];
    const float* dec_self_b = (const float*)d_in[15];
    const float* dec_cross_w= (const float*)d_in[16];
    const float* dec_cross_b= (const float*)d_in[17];
    const float* dec_ffn_w1 = (const float*)d_in[18];
    const float* dec_ffn_b1 = (const float*)d_in[19];
    const float* dec_ffn_w2 = (const float*)d_in[20];
    const float* dec_ffn_b2 = (const float*)d_in[21];
    const float* dec_ln_s   = (const float*)d_in[22];
    const float* dec_ln_b   = (const float*)d_in[23];
    const float* out_w      = (const float*)d_in[24];
    const float* out_b      = (const float*)d_in[25];
    float* out = (float*)d_out;

    // Workspace layout (floats). Total = 38,600,704 fl = 147.3 MB.
    const size_t SZ_BSD = (size_t)B_ * S_ * D_;   // 8,388,608
    const size_t SZ_BTD = (size_t)B_ * T_ * D_;   // 2,949,120
    const int    CH     = 4096;                   // M-chunk for o/mid reuse
    float* ws   = (float*)d_ws;
    float* h    = ws;                  // encoder state -> memory (persists)
    float* q    = h + SZ_BSD;          // q / attn-out (in-place); FFN mid alias
    float* k    = q + SZ_BSD;
    float* v    = k + SZ_BSD;
    float* o    = v + SZ_BSD;          // CH x D chunk buffer (2,097,152 fl)
    float* dbuf = o + (size_t)CH * D_; // decoder state
    float* mid  = q;                   // FFN hidden aliases q..v (dead there)

    const int MS = B_ * S_;   // 16384
    const int MT = B_ * T_;   // 5760

    auto gemm = [&](const float* A, const float* W, const float* bi, float* C,
                    int M, int N, int K, int relu) {
        dim3 g(N / 64, M / 64);
        gemm_kernel<<<g, dim3(256), 0, stream>>>(A, W, bi, C, M, N, K, relu);
    };
    auto attn = [&](const float* Qp, const float* Kp, const float* Vp, float* Op,
                    int Sq, int Sk, int causal) {
        dim3 g((Sq + QB - 1) / QB, H_, B_);
        attn_kernel<<<g, dim3(256), 0, stream>>>(Qp, Kp, Vp, Op, Sq, Sk, causal);
    };
    auto addln = [&](float* hp, const float* dp, const float* sc, const float* bi,
                     int rows) {
        add_ln_kernel<<<dim3(rows), dim3(128), 0, stream>>>(hp, dp, sc, bi);
    };
    // chunked: state = LN(state + A @ W + b)
    auto proj_addln = [&](float* state, const float* A, const float* W,
                          const float* bi, const float* lns, const float* lnb,
                          int M) {
        for (int m0 = 0; m0 < M; m0 += CH) {
            int mlen = (M - m0 < CH) ? (M - m0) : CH;
            gemm(A + (size_t)m0 * D_, W, bi, o, mlen, D_, D_, 0);
            addln(state + (size_t)m0 * D_, o, lns, lnb, mlen);
        }
    };
    // chunked: state = LN(state + relu(state@W1+b1)@W2+b2)
    auto ffn_addln = [&](float* state, const float* W1, const float* b1,
                         const float* W2, const float* b2,
                         const float* lns, const float* lnb, int M) {
        for (int m0 = 0; m0 < M; m0 += CH) {
            int mlen = (M - m0 < CH) ? (M - m0) : CH;
            gemm(state + (size_t)m0 * D_, W1, b1, mid, mlen, F_, D_, 1);
            gemm(mid, W2, b2, o, mlen, D_, F_, 0);
            addln(state + (size_t)m0 * D_, o, lns, lnb, mlen);
        }
    };

    // ---- encoder ----
    embed_src_kernel<<<dim3((B_ * S_ * D_ + 255) / 256), dim3(256), 0, stream>>>(
        x, src_w, src_b, h);
    for (int l = 0; l < L_; ++l) {
        const float* wl = enc_attn_w + (size_t)l * 4 * D_ * D_;
        const float* bl = enc_attn_b + (size_t)l * 4 * D_;
        gemm(h, wl + 0 * D_ * D_, bl + 0 * D_, q, MS, D_, D_, 0);
        gemm(h, wl + 1 * D_ * D_, bl + 1 * D_, k, MS, D_, D_, 0);
        gemm(h, wl + 2 * D_ * D_, bl + 2 * D_, v, MS, D_, D_, 0);
        attn(q, k, v, q, S_, S_, 0);                       // in-place
        proj_addln(h, q, wl + 3 * D_ * D_, bl + 3 * D_,
                   enc_ln_s + (size_t)l * 2 * D_, enc_ln_b + (size_t)l * 2 * D_, MS);
        ffn_addln(h, enc_ffn_w1 + (size_t)l * D_ * F_, enc_ffn_b1 + (size_t)l * F_,
                  enc_ffn_w2 + (size_t)l * F_ * D_, enc_ffn_b2 + (size_t)l * D_,
                  enc_ln_s + (size_t)l * 2 * D_ + D_,
                  enc_ln_b + (size_t)l * 2 * D_ + D_, MS);
    }
    // h == memory from here on (not overwritten).

    // ---- decoder ----
    embed_tgt_kernel<<<dim3((B_ * T_ * D_ + 255) / 256), dim3(256), 0, stream>>>(
        y, tgt_w, tgt_b, dbuf);
    for (int l = 0; l < L_; ++l) {
        const float* wl = dec_self_w + (size_t)l * 4 * D_ * D_;
        const float* bl = dec_self_b + (size_t)l * 4 * D_;
        gemm(dbuf, wl + 0 * D_ * D_, bl + 0 * D_, q, MT, D_, D_, 0);
        gemm(dbuf, wl + 1 * D_ * D_, bl + 1 * D_, k, MT, D_, D_, 0);
        gemm(dbuf, wl + 2 * D_ * D_, bl + 2 * D_, v, MT, D_, D_, 0);
        attn(q, k, v, q, T_, T_, 1);                       // in-place, causal
        proj_addln(dbuf, q, wl + 3 * D_ * D_, bl + 3 * D_,
                   dec_ln_s + (size_t)l * 3 * D_, dec_ln_b + (size_t)l * 3 * D_, MT);

        const float* wc = dec_cross_w + (size_t)l * 4 * D_ * D_;
        const float* bc = dec_cross_b + (size_t)l * 4 * D_;
        gemm(dbuf, wc + 0 * D_ * D_, bc + 0 * D_, q, MT, D_, D_, 0);
        gemm(h,    wc + 1 * D_ * D_, bc + 1 * D_, k, MS, D_, D_, 0);
        gemm(h,    wc + 2 * D_ * D_, bc + 2 * D_, v, MS, D_, D_, 0);
        attn(q, k, v, q, T_, S_, 0);                       // in-place
        proj_addln(dbuf, q, wc + 3 * D_ * D_, bc + 3 * D_,
                   dec_ln_s + (size_t)l * 3 * D_ + D_,
                   dec_ln_b + (size_t)l * 3 * D_ + D_, MT);

        ffn_addln(dbuf, dec_ffn_w1 + (size_t)l * D_ * F_, dec_ffn_b1 + (size_t)l * F_,
                  dec_ffn_w2 + (size_t)l * F_ * D_, dec_ffn_b2 + (size_t)l * D_,
                  dec_ln_s + (size_t)l * 3 * D_ + 2 * D_,
                  dec_ln_b + (size_t)l * 3 * D_ + 2 * D_, MT);
    }

    out_proj_kernel<<<dim3(MT), dim3(64), 0, stream>>>(dbuf, out_w, out_b, out);
}

// Round 3
// 12377.563 us; speedup vs baseline: 1.9778x; 1.9778x over previous
//
#include <hip/hip_runtime.h>
#include <math.h>

// Problem constants (TransformerController)
#define B_  32
#define S_  512
#define T_  180
#define D_  512
#define F_  2048
#define L_  6
#define H_  8
#define DH_ 64

typedef unsigned short u16;
typedef __attribute__((ext_vector_type(8))) short short8;   // 8 x bf16 (4 VGPR)
typedef __attribute__((ext_vector_type(4))) float floatx4;  // MFMA acc

__device__ __forceinline__ float bf2f(u16 h) {
    union { unsigned u; float f; } un; un.u = ((unsigned)h) << 16; return un.f;
}
__device__ __forceinline__ u16 f2bf(float f) {
    union { float f; unsigned u; } un; un.f = f;
    unsigned u = un.u;
    u += 0x7fffu + ((u >> 16) & 1u);   // RNE
    return (u16)(u >> 16);
}

// async global->LDS, 16B per lane, dest = wave-uniform base + lane*16
__device__ __forceinline__ void gload16(const u16* g, u16* l) {
    __builtin_amdgcn_global_load_lds(
        (const __attribute__((address_space(1))) void*)g,
        (__attribute__((address_space(3))) void*)l, 16, 0, 0);
}

// ---------------------------------------------------------------------------
// Embedding kernels -> bf16
// ---------------------------------------------------------------------------
__device__ __forceinline__ float pos_enc(int pos, int c) {
    int i2 = c & ~1;
    float div = expf(-(float)i2 * (9.210340371976184f / 512.0f));
    float arg = (float)pos * div;
    return (c & 1) ? cosf(arg) : sinf(arg);
}

__global__ __launch_bounds__(256) void embed_src_kernel(
    const float* __restrict__ x, const float* __restrict__ w,
    const float* __restrict__ b, u16* __restrict__ h)
{
    int idx = blockIdx.x * 256 + threadIdx.x;
    if (idx >= B_ * S_ * D_) return;
    int c  = idx & (D_ - 1);
    int bs = idx >> 9;
    int s  = bs & (S_ - 1);
    float x0 = x[bs * 2 + 0];
    float x1 = x[bs * 2 + 1];
    h[idx] = f2bf(x0 * w[c] + x1 * w[D_ + c] + b[c] + pos_enc(s, c));
}

__global__ __launch_bounds__(256) void embed_tgt_kernel(
    const float* __restrict__ y, const float* __restrict__ w,
    const float* __restrict__ b, u16* __restrict__ d)
{
    int idx = blockIdx.x * 256 + threadIdx.x;
    if (idx >= B_ * T_ * D_) return;
    int c  = idx & (D_ - 1);
    int bt = idx >> 9;
    int t  = bt % T_;
    int bb = bt / T_;
    float tv = (t == 0) ? 0.0f : y[bb * T_ + (t - 1)];
    d[idx] = f2bf(tv * w[c] + b[c] + pos_enc(t, c));
}

// ---------------------------------------------------------------------------
// Weight convert+transpose: W[K,N] fp32 -> Wt[N,K] bf16. blockIdx.z = matrix.
// ---------------------------------------------------------------------------
__global__ __launch_bounds__(256) void wconv_kernel(
    const float* __restrict__ W, u16* __restrict__ Wt, int K, int N)
{
    __shared__ float tile[32][33];
    size_t mat = (size_t)blockIdx.z * K * N;
    const float* Wm = W + mat;
    u16* Wtm = Wt + mat;
    int n0 = blockIdx.x * 32, k0 = blockIdx.y * 32;
    int tx = threadIdx.x & 31, ty = threadIdx.x >> 5;   // ty 0..7
#pragma unroll
    for (int i = 0; i < 32; i += 8)
        tile[ty + i][tx] = Wm[(size_t)(k0 + ty + i) * N + n0 + tx];
    __syncthreads();
#pragma unroll
    for (int i = 0; i < 32; i += 8)
        Wtm[(size_t)(n0 + ty + i) * K + k0 + tx] = f2bf(tile[tx][ty + i]);
}

// ---------------------------------------------------------------------------
// bf16 MFMA GEMM: C[M,N] = act(A[M,K] @ Wt[N,K]^T + bias), bf16 in/out,
// fp32 accumulate. 128x128 tile, BK=32, 256 threads (4 waves, 2x2 of 64x64).
// M,N multiples of 128; K multiple of 32. Staging via global_load_lds x16.
// ---------------------------------------------------------------------------
__global__ __launch_bounds__(256) void gemm_bf16_kernel(
    const u16* __restrict__ A, const u16* __restrict__ Bt,
    const float* __restrict__ bias, u16* __restrict__ C,
    int M, int N, int K, int relu)
{
    __shared__ u16 As[128 * 32];   // [row][k] row-major, 8 KB
    __shared__ u16 Bs[128 * 32];

    int tid  = threadIdx.x;
    int w    = tid >> 6;
    int lane = tid & 63;
    int m0 = blockIdx.y << 7, n0 = blockIdx.x << 7;

    // staging: instruction t in {0,1} per wave; 16 rows per instr, 4 lanes/row
    int sr = w * 32 + (lane >> 2);        // row within tile (+16 for t=1)
    int sk = (lane & 3) * 8;              // k offset (8 bf16 = 16 B)
    const u16* ag0 = A  + (size_t)(m0 + sr)      * K + sk;
    const u16* ag1 = A  + (size_t)(m0 + sr + 16) * K + sk;
    const u16* bg0 = Bt + (size_t)(n0 + sr)      * K + sk;
    const u16* bg1 = Bt + (size_t)(n0 + sr + 16) * K + sk;
    u16* al0 = As + (w * 2 + 0) * 512;    // wave-uniform LDS bases
    u16* al1 = As + (w * 2 + 1) * 512;
    u16* bl0 = Bs + (w * 2 + 0) * 512;
    u16* bl1 = Bs + (w * 2 + 1) * 512;

    // compute mapping: wave -> 64x64 quadrant; 4x4 grid of 16x16x32 MFMAs
    int wm = (w >> 1) * 64, wn = (w & 1) * 64;
    int fr = lane & 15;                   // row (A) / col (B) within 16
    int fk = (lane >> 4) * 8;             // k offset within 32

    floatx4 acc[4][4] = {};

    for (int k0 = 0; k0 < K; k0 += 32) {
        gload16(ag0 + k0, al0);
        gload16(ag1 + k0, al1);
        gload16(bg0 + k0, bl0);
        gload16(bg1 + k0, bl1);
        __syncthreads();

        short8 af[4], bf[4];
#pragma unroll
        for (int i = 0; i < 4; ++i)
            af[i] = *(const short8*)&As[(wm + i * 16 + fr) * 32 + fk];
#pragma unroll
        for (int j = 0; j < 4; ++j)
            bf[j] = *(const short8*)&Bs[(wn + j * 16 + fr) * 32 + fk];
#pragma unroll
        for (int i = 0; i < 4; ++i)
#pragma unroll
            for (int j = 0; j < 4; ++j)
                acc[i][j] = __builtin_amdgcn_mfma_f32_16x16x32_bf16(
                    af[i], bf[j], acc[i][j], 0, 0, 0);
        __syncthreads();
    }

    // epilogue: C/D layout col=lane&15, row=(lane>>4)*4+reg
    int cc = lane & 15;
    int rq = (lane >> 4) * 4;
#pragma unroll
    for (int j = 0; j < 4; ++j) {
        int col = n0 + wn + j * 16 + cc;
        float bj = bias[col];
#pragma unroll
        for (int i = 0; i < 4; ++i) {
#pragma unroll
            for (int r = 0; r < 4; ++r) {
                int row = m0 + wm + i * 16 + rq + r;
                float vv = acc[i][j][r] + bj;
                if (relu) vv = fmaxf(vv, 0.f);
                C[(size_t)row * N + col] = f2bf(vv);
            }
        }
    }
}

// ---------------------------------------------------------------------------
// Flash-style attention, bf16 in/out, fp32 compute. IN-PLACE capable
// (O may alias Q). One block = (b, h, 16-query tile); 64-key tiles.
// ---------------------------------------------------------------------------
#define QB 16
#define KB 64

__global__ __launch_bounds__(256) void attn_kernel(
    const u16* Q, const u16* __restrict__ K,
    const u16* __restrict__ V, u16* O,
    int Sq, int Sk, int causal)
{
    __shared__ __align__(16) float Qs[QB][68];
    __shared__ __align__(16) float Ks[KB][68];
    __shared__ __align__(16) float Vs[KB][68];
    __shared__ float Ps[QB][65];
    __shared__ float m_s[QB], l_s[QB], mnew_s[QB], alpha_s[QB];

    int tid = threadIdx.x;
    int qi = tid >> 4;
    int ci = tid & 15;
    int q0 = blockIdx.x * QB;
    int hh = blockIdx.y;
    int bb = blockIdx.z;

    const u16* Qb = Q + (size_t)bb * Sq * D_ + hh * DH_;
    const u16* Kb = K + (size_t)bb * Sk * D_ + hh * DH_;
    const u16* Vb = V + (size_t)bb * Sk * D_ + hh * DH_;

    for (int idx = tid; idx < QB * DH_; idx += 256) {
        int r = idx >> 6, c = idx & 63;
        int qg = q0 + r;
        Qs[r][c] = (qg < Sq) ? bf2f(Qb[(size_t)qg * D_ + c]) : 0.0f;
    }
    if (tid < QB) { m_s[tid] = -1e30f; l_s[tid] = 0.0f; }
    float acc0 = 0.f, acc1 = 0.f, acc2 = 0.f, acc3 = 0.f;
    __syncthreads();

    int kend = causal ? ((Sk < q0 + QB) ? Sk : (q0 + QB)) : Sk;
    for (int k0 = 0; k0 < kend; k0 += KB) {
        // stage K/V as uint (2 bf16) loads
        for (int idx = tid; idx < KB * DH_ / 2; idx += 256) {
            int r = idx >> 5, c2 = (idx & 31) * 2;
            int kg = k0 + r;
            if (kg < Sk) {
                unsigned kk = *(const unsigned*)&Kb[(size_t)kg * D_ + c2];
                unsigned vv = *(const unsigned*)&Vb[(size_t)kg * D_ + c2];
                Ks[r][c2] = bf2f(kk & 0xffff); Ks[r][c2 + 1] = bf2f(kk >> 16);
                Vs[r][c2] = bf2f(vv & 0xffff); Vs[r][c2 + 1] = bf2f(vv >> 16);
            } else {
                Ks[r][c2] = 0.f; Ks[r][c2 + 1] = 0.f;
                Vs[r][c2] = 0.f; Vs[r][c2 + 1] = 0.f;
            }
        }
        __syncthreads();

        float s0 = 0.f, s1 = 0.f, s2 = 0.f, s3 = 0.f;
#pragma unroll
        for (int dc = 0; dc < DH_; dc += 4) {
            float4 q4 = *(const float4*)&Qs[qi][dc];
            float4 k0v = *(const float4*)&Ks[ci][dc];
            float4 k1v = *(const float4*)&Ks[ci + 16][dc];
            float4 k2v = *(const float4*)&Ks[ci + 32][dc];
            float4 k3v = *(const float4*)&Ks[ci + 48][dc];
            s0 += q4.x * k0v.x + q4.y * k0v.y + q4.z * k0v.z + q4.w * k0v.w;
            s1 += q4.x * k1v.x + q4.y * k1v.y + q4.z * k1v.z + q4.w * k1v.w;
            s2 += q4.x * k2v.x + q4.y * k2v.y + q4.z * k2v.z + q4.w * k2v.w;
            s3 += q4.x * k3v.x + q4.y * k3v.y + q4.z * k3v.z + q4.w * k3v.w;
        }
        int qg = q0 + qi;
        {
            int kg;
            kg = k0 + ci;
            Ps[qi][ci]      = (kg >= Sk || (causal && kg > qg)) ? -1e9f : s0 * 0.125f;
            kg = k0 + ci + 16;
            Ps[qi][ci + 16] = (kg >= Sk || (causal && kg > qg)) ? -1e9f : s1 * 0.125f;
            kg = k0 + ci + 32;
            Ps[qi][ci + 32] = (kg >= Sk || (causal && kg > qg)) ? -1e9f : s2 * 0.125f;
            kg = k0 + ci + 48;
            Ps[qi][ci + 48] = (kg >= Sk || (causal && kg > qg)) ? -1e9f : s3 * 0.125f;
        }
        __syncthreads();

        if (ci == 0) {
            float mx = m_s[qi];
#pragma unroll
            for (int j = 0; j < KB; ++j) mx = fmaxf(mx, Ps[qi][j]);
            mnew_s[qi] = mx;
            alpha_s[qi] = expf(m_s[qi] - mx);
        }
        __syncthreads();

        float mn = mnew_s[qi];
        Ps[qi][ci]      = expf(Ps[qi][ci]      - mn);
        Ps[qi][ci + 16] = expf(Ps[qi][ci + 16] - mn);
        Ps[qi][ci + 32] = expf(Ps[qi][ci + 32] - mn);
        Ps[qi][ci + 48] = expf(Ps[qi][ci + 48] - mn);
        __syncthreads();

        if (ci == 0) {
            float sum = 0.f;
#pragma unroll
            for (int j = 0; j < KB; ++j) sum += Ps[qi][j];
            l_s[qi] = l_s[qi] * alpha_s[qi] + sum;
            m_s[qi] = mnew_s[qi];
        }
        float al = alpha_s[qi];
        acc0 *= al; acc1 *= al; acc2 *= al; acc3 *= al;
#pragma unroll
        for (int kj = 0; kj < KB; ++kj) {
            float p = Ps[qi][kj];
            float4 v4 = *(const float4*)&Vs[kj][ci * 4];
            acc0 = fmaf(p, v4.x, acc0);
            acc1 = fmaf(p, v4.y, acc1);
            acc2 = fmaf(p, v4.z, acc2);
            acc3 = fmaf(p, v4.w, acc3);
        }
        __syncthreads();
    }

    int qg = q0 + qi;
    if (qg < Sq) {
        float inv = 1.0f / l_s[qi];
        u16* Op = O + (size_t)bb * Sq * D_ + (size_t)qg * D_ + hh * DH_ + ci * 4;
        Op[0] = f2bf(acc0 * inv); Op[1] = f2bf(acc1 * inv);
        Op[2] = f2bf(acc2 * inv); Op[3] = f2bf(acc3 * inv);
    }
}

// ---------------------------------------------------------------------------
// h[row,:] = LN(h[row,:] + delta[row,:]) * scale + bias (bf16 io, fp32 math)
// ---------------------------------------------------------------------------
__global__ __launch_bounds__(128) void add_ln_kernel(
    u16* __restrict__ h, const u16* __restrict__ delta,
    const float* __restrict__ scale, const float* __restrict__ bias)
{
    __shared__ float red[128];
    int row = blockIdx.x, tid = threadIdx.x;
    size_t base = (size_t)row * D_ + tid * 4;
    uint2 hv = *(const uint2*)&h[base];
    uint2 dv = *(const uint2*)&delta[base];
    float v0 = bf2f(hv.x & 0xffff) + bf2f(dv.x & 0xffff);
    float v1 = bf2f(hv.x >> 16)    + bf2f(dv.x >> 16);
    float v2 = bf2f(hv.y & 0xffff) + bf2f(dv.y & 0xffff);
    float v3 = bf2f(hv.y >> 16)    + bf2f(dv.y >> 16);

    red[tid] = v0 + v1 + v2 + v3;
    __syncthreads();
    for (int off = 64; off > 0; off >>= 1) {
        if (tid < off) red[tid] += red[tid + off];
        __syncthreads();
    }
    float mu = red[0] * (1.0f / 512.0f);
    __syncthreads();

    float d0 = v0 - mu, d1 = v1 - mu, d2 = v2 - mu, d3 = v3 - mu;
    red[tid] = d0 * d0 + d1 * d1 + d2 * d2 + d3 * d3;
    __syncthreads();
    for (int off = 64; off > 0; off >>= 1) {
        if (tid < off) red[tid] += red[tid + off];
        __syncthreads();
    }
    float var = red[0] * (1.0f / 512.0f);
    float rs = rsqrtf(var + 1e-5f);

    int c = tid * 4;
    float4 sc = *(const float4*)&scale[c];
    float4 bi = *(const float4*)&bias[c];
    unsigned lo = (unsigned)f2bf(d0 * rs * sc.x + bi.x) |
                  ((unsigned)f2bf(d1 * rs * sc.y + bi.y) << 16);
    unsigned hi = (unsigned)f2bf(d2 * rs * sc.z + bi.z) |
                  ((unsigned)f2bf(d3 * rs * sc.w + bi.w) << 16);
    *(uint2*)&h[base] = make_uint2(lo, hi);
}

// ---------------------------------------------------------------------------
// out[row] = d[row,:] . w[:] + b   (one wave per row; d bf16, out fp32)
// ---------------------------------------------------------------------------
__global__ __launch_bounds__(64) void out_proj_kernel(
    const u16* __restrict__ d, const float* __restrict__ w,
    const float* __restrict__ b, float* __restrict__ out)
{
    int row = blockIdx.x, lane = threadIdx.x;
    float s = 0.f;
    for (int c = lane; c < D_; c += 64) s += bf2f(d[(size_t)row * D_ + c]) * w[c];
#pragma unroll
    for (int off = 32; off > 0; off >>= 1) s += __shfl_down(s, off);
    if (lane == 0) out[row] = s + b[0];
}

// ---------------------------------------------------------------------------
// Host orchestration
// ---------------------------------------------------------------------------
extern "C" void kernel_launch(void* const* d_in, const int* in_sizes, int n_in,
                              void* d_out, int out_size, void* d_ws, size_t ws_size,
                              hipStream_t stream)
{
    const float* x          = (const float*)d_in[0];
    const float* y          = (const float*)d_in[1];
    const float* src_w      = (const float*)d_in[2];
    const float* src_b      = (const float*)d_in[3];
    const float* tgt_w      = (const float*)d_in[4];
    const float* tgt_b      = (const float*)d_in[5];
    const float* enc_attn_w = (const float*)d_in[6];
    const float* enc_attn_b = (const float*)d_in[7];
    const float* enc_ffn_w1 = (const float*)d_in[8];
    const float* enc_ffn_b1 = (const float*)d_in[9];
    const float* enc_ffn_w2 = (const float*)d_in[10];
    const float* enc_ffn_b2 = (const float*)d_in[11];
    const float* enc_ln_s   = (const float*)d_in[12];
    const float* enc_ln_b   = (const float*)d_in[13];
    const float* dec_self_w = (const float*)d_in[14];
    const float* dec_self_b = (const float*)d_in[15];
    const float* dec_cross_w= (const float*)d_in[16];
    const float* dec_cross_b= (const float*)d_in[17];
    const float* dec_ffn_w1 = (const float*)d_in[18];
    const float* dec_ffn_b1 = (const float*)d_in[19];
    const float* dec_ffn_w2 = (const float*)d_in[20];
    const float* dec_ffn_b2 = (const float*)d_in[21];
    const float* dec_ln_s   = (const float*)d_in[22];
    const float* dec_ln_b   = (const float*)d_in[23];
    const float* out_w      = (const float*)d_in[24];
    const float* out_b      = (const float*)d_in[25];
    float* out = (float*)d_out;

    // Workspace (u16 elems). Total = 42,795,008 u16 = 85.6 MB.
    const size_t E_BSD = (size_t)B_ * S_ * D_;   // 8,388,608
    const size_t E_BTD = (size_t)B_ * T_ * D_;   // 2,949,120
    const int    CH    = 4096;                   // M-chunk (mult of 128)
    const size_t WDD   = (size_t)D_ * D_;        // 262,144
    const size_t WDF   = (size_t)D_ * F_;        // 1,048,576
    u16* h    = (u16*)d_ws;
    u16* q    = h + E_BSD;
    u16* k    = q + E_BSD;
    u16* v    = k + E_BSD;
    u16* o    = v + E_BSD;               // CH x D chunk out (2,097,152)
    u16* dbuf = o + (size_t)CH * D_;
    u16* wsc  = dbuf + E_BTD;            // per-layer weight scratch (4,194,304)
    u16* mid  = q;                       // FFN hidden aliases q (dead there)

    const int MS = B_ * S_;   // 16384
    const int MT = B_ * T_;   // 5760

    auto gemm = [&](const u16* A, const u16* Wt, const float* bi, u16* C,
                    int M, int N, int K, int relu) {
        dim3 g(N / 128, M / 128);
        gemm_bf16_kernel<<<g, dim3(256), 0, stream>>>(A, Wt, bi, C, M, N, K, relu);
    };
    auto attn = [&](const u16* Qp, const u16* Kp, const u16* Vp, u16* Op,
                    int Sq, int Sk, int causal) {
        dim3 g((Sq + QB - 1) / QB, H_, B_);
        attn_kernel<<<g, dim3(256), 0, stream>>>(Qp, Kp, Vp, Op, Sq, Sk, causal);
    };
    auto addln = [&](u16* hp, const u16* dp, const float* sc, const float* bi,
                     int rows) {
        add_ln_kernel<<<dim3(rows), dim3(128), 0, stream>>>(hp, dp, sc, bi);
    };
    auto wconv = [&](const float* W, u16* Wt, int K, int N, int nmat) {
        wconv_kernel<<<dim3(N / 32, K / 32, nmat), dim3(256), 0, stream>>>(W, Wt, K, N);
    };
    // chunked: state = LN(state + A @ Wt^T + b)
    auto proj_addln = [&](u16* state, const u16* A, const u16* Wt,
                          const float* bi, const float* lns, const float* lnb,
                          int M) {
        for (int m0 = 0; m0 < M; m0 += CH) {
            int mlen = (M - m0 < CH) ? (M - m0) : CH;
            gemm(A + (size_t)m0 * D_, Wt, bi, o, mlen, D_, D_, 0);
            addln(state + (size_t)m0 * D_, o, lns, lnb, mlen);
        }
    };
    // chunked: state = LN(state + relu(state@W1+b1)@W2+b2)
    auto ffn_addln = [&](u16* state, const u16* Wt1, const float* b1,
                         const u16* Wt2, const float* b2,
                         const float* lns, const float* lnb, int M) {
        for (int m0 = 0; m0 < M; m0 += CH) {
            int mlen = (M - m0 < CH) ? (M - m0) : CH;
            gemm(state + (size_t)m0 * D_, Wt1, b1, mid, mlen, F_, D_, 1);
            gemm(mid, Wt2, b2, o, mlen, D_, F_, 0);
            addln(state + (size_t)m0 * D_, o, lns, lnb, mlen);
        }
    };

    // ---- encoder ----
    embed_src_kernel<<<dim3((B_ * S_ * D_ + 255) / 256), dim3(256), 0, stream>>>(
        x, src_w, src_b, h);
    for (int l = 0; l < L_; ++l) {
        // convert this layer's weights: [4 attn][ffn1][ffn2]
        wconv(enc_attn_w + (size_t)l * 4 * WDD, wsc, D_, D_, 4);
        wconv(enc_ffn_w1 + (size_t)l * WDF, wsc + 4 * WDD, D_, F_, 1);
        wconv(enc_ffn_w2 + (size_t)l * WDF, wsc + 4 * WDD + WDF, F_, D_, 1);

        const float* bl = enc_attn_b + (size_t)l * 4 * D_;
        gemm(h, wsc + 0 * WDD, bl + 0 * D_, q, MS, D_, D_, 0);
        gemm(h, wsc + 1 * WDD, bl + 1 * D_, k, MS, D_, D_, 0);
        gemm(h, wsc + 2 * WDD, bl + 2 * D_, v, MS, D_, D_, 0);
        attn(q, k, v, q, S_, S_, 0);                       // in-place
        proj_addln(h, q, wsc + 3 * WDD, bl + 3 * D_,
                   enc_ln_s + (size_t)l * 2 * D_, enc_ln_b + (size_t)l * 2 * D_, MS);
        ffn_addln(h, wsc + 4 * WDD, enc_ffn_b1 + (size_t)l * F_,
                  wsc + 4 * WDD + WDF, enc_ffn_b2 + (size_t)l * D_,
                  enc_ln_s + (size_t)l * 2 * D_ + D_,
                  enc_ln_b + (size_t)l * 2 * D_ + D_, MS);
    }
    // h == memory from here on.

    // ---- decoder ----
    embed_tgt_kernel<<<dim3((B_ * T_ * D_ + 255) / 256), dim3(256), 0, stream>>>(
        y, tgt_w, tgt_b, dbuf);
    for (int l = 0; l < L_; ++l) {
        // weights: [4 self][4 cross][ffn1][ffn2]
        wconv(dec_self_w  + (size_t)l * 4 * WDD, wsc, D_, D_, 4);
        wconv(dec_cross_w + (size_t)l * 4 * WDD, wsc + 4 * WDD, D_, D_, 4);
        wconv(dec_ffn_w1  + (size_t)l * WDF, wsc + 8 * WDD, D_, F_, 1);
        wconv(dec_ffn_w2  + (size_t)l * WDF, wsc + 8 * WDD + WDF, F_, D_, 1);

        const float* bl = dec_self_b + (size_t)l * 4 * D_;
        gemm(dbuf, wsc + 0 * WDD, bl + 0 * D_, q, MT, D_, D_, 0);
        gemm(dbuf, wsc + 1 * WDD, bl + 1 * D_, k, MT, D_, D_, 0);
        gemm(dbuf, wsc + 2 * WDD, bl + 2 * D_, v, MT, D_, D_, 0);
        attn(q, k, v, q, T_, T_, 1);                       // in-place, causal
        proj_addln(dbuf, q, wsc + 3 * WDD, bl + 3 * D_,
                   dec_ln_s + (size_t)l * 3 * D_, dec_ln_b + (size_t)l * 3 * D_, MT);

        const float* bc = dec_cross_b + (size_t)l * 4 * D_;
        gemm(dbuf, wsc + 4 * WDD, bc + 0 * D_, q, MT, D_, D_, 0);
        gemm(h,    wsc + 5 * WDD, bc + 1 * D_, k, MS, D_, D_, 0);
        gemm(h,    wsc + 6 * WDD, bc + 2 * D_, v, MS, D_, D_, 0);
        attn(q, k, v, q, T_, S_, 0);                       // in-place
        proj_addln(dbuf, q, wsc + 7 * WDD, bc + 3 * D_,
                   dec_ln_s + (size_t)l * 3 * D_ + D_,
                   dec_ln_b + (size_t)l * 3 * D_ + D_, MT);

        ffn_addln(dbuf, wsc + 8 * WDD, dec_ffn_b1 + (size_t)l * F_,
                  wsc + 8 * WDD + WDF, dec_ffn_b2 + (size_t)l * D_,
                  dec_ln_s + (size_t)l * 3 * D_ + 2 * D_,
                  dec_ln_b + (size_t)l * 3 * D_ + 2 * D_, MT);
    }

    out_proj_kernel<<<dim3(MT), dim3(64), 0, stream>>>(dbuf, out_w, out_b, out);
}

// Round 4
// 8182.283 us; speedup vs baseline: 2.9919x; 1.5127x over previous
//
#include <hip/hip_runtime.h>
#include <math.h>

// Problem constants (TransformerController)
#define B_  32
#define S_  512
#define T_  180
#define D_  512
#define F_  2048
#define L_  6
#define H_  8
#define DH_ 64

typedef unsigned short u16;
typedef __attribute__((ext_vector_type(8))) short short8;   // 8 x bf16
typedef __attribute__((ext_vector_type(4))) float floatx4;  // MFMA acc

__device__ __forceinline__ float bf2f(u16 h) {
    union { unsigned u; float f; } un; un.u = ((unsigned)h) << 16; return un.f;
}
__device__ __forceinline__ u16 f2bf(float f) {
    union { float f; unsigned u; } un; un.f = f;
    unsigned u = un.u;
    u += 0x7fffu + ((u >> 16) & 1u);   // RNE
    return (u16)(u >> 16);
}

// async global->LDS, 16B per lane, dest = wave-uniform base + lane*16
__device__ __forceinline__ void gload16(const u16* g, u16* l) {
    __builtin_amdgcn_global_load_lds(
        (const __attribute__((address_space(1))) void*)g,
        (__attribute__((address_space(3))) void*)l, 16, 0, 0);
}

// ---------------------------------------------------------------------------
// Embedding kernels -> bf16
// ---------------------------------------------------------------------------
__device__ __forceinline__ float pos_enc(int pos, int c) {
    int i2 = c & ~1;
    float div = expf(-(float)i2 * (9.210340371976184f / 512.0f));
    float arg = (float)pos * div;
    return (c & 1) ? cosf(arg) : sinf(arg);
}

__global__ __launch_bounds__(256) void embed_src_kernel(
    const float* __restrict__ x, const float* __restrict__ w,
    const float* __restrict__ b, u16* __restrict__ h)
{
    int idx = blockIdx.x * 256 + threadIdx.x;
    if (idx >= B_ * S_ * D_) return;
    int c  = idx & (D_ - 1);
    int bs = idx >> 9;
    int s  = bs & (S_ - 1);
    float x0 = x[bs * 2 + 0];
    float x1 = x[bs * 2 + 1];
    h[idx] = f2bf(x0 * w[c] + x1 * w[D_ + c] + b[c] + pos_enc(s, c));
}

__global__ __launch_bounds__(256) void embed_tgt_kernel(
    const float* __restrict__ y, const float* __restrict__ w,
    const float* __restrict__ b, u16* __restrict__ d)
{
    int idx = blockIdx.x * 256 + threadIdx.x;
    if (idx >= B_ * T_ * D_) return;
    int c  = idx & (D_ - 1);
    int bt = idx >> 9;
    int t  = bt % T_;
    int bb = bt / T_;
    float tv = (t == 0) ? 0.0f : y[bb * T_ + (t - 1)];
    d[idx] = f2bf(tv * w[c] + b[c] + pos_enc(t, c));
}

// ---------------------------------------------------------------------------
// Weight convert+transpose: W[K,N] fp32 -> Wt[N,K] bf16. blockIdx.z = matrix.
// ---------------------------------------------------------------------------
__global__ __launch_bounds__(256) void wconv_kernel(
    const float* __restrict__ W, u16* __restrict__ Wt, int K, int N)
{
    __shared__ float tile[32][33];
    size_t mat = (size_t)blockIdx.z * K * N;
    const float* Wm = W + mat;
    u16* Wtm = Wt + mat;
    int n0 = blockIdx.x * 32, k0 = blockIdx.y * 32;
    int tx = threadIdx.x & 31, ty = threadIdx.x >> 5;   // ty 0..7
#pragma unroll
    for (int i = 0; i < 32; i += 8)
        tile[ty + i][tx] = Wm[(size_t)(k0 + ty + i) * N + n0 + tx];
    __syncthreads();
#pragma unroll
    for (int i = 0; i < 32; i += 8)
        Wtm[(size_t)(n0 + ty + i) * K + k0 + tx] = f2bf(tile[tx][ty + i]);
}

// ---------------------------------------------------------------------------
// bf16 MFMA GEMM: C[M,N] = act(A[M,K](lda) @ Wt[N,K]^T + bias), bf16 io,
// fp32 acc. 128x128 tile, BK=32, 256 thr (4 waves, 2x2 of 64x64 quadrants).
// M,N mult of 128; K mult of 32. LDS-bounce epilogue -> coalesced 16B stores.
// ---------------------------------------------------------------------------
__global__ __launch_bounds__(256) void gemm_bf16_kernel(
    const u16* __restrict__ A, int lda, const u16* __restrict__ Bt,
    const float* __restrict__ bias, u16* __restrict__ C, int ldc,
    int M, int N, int K, int relu)
{
    // As/Bs: 128x32 each (8 KB each). epi: 4 waves x 64 rows x 72 u16 = 36 KB.
    __shared__ u16 smem[18432];
    u16* As = smem;
    u16* Bs = smem + 4096;

    int tid  = threadIdx.x;
    int w    = tid >> 6;
    int lane = tid & 63;
    int m0 = blockIdx.y << 7, n0 = blockIdx.x << 7;

    // staging: per wave 2 instrs for A, 2 for B; 16 rows/instr, 4 lanes/row
    int sr = w * 32 + (lane >> 2);
    int sk = (lane & 3) * 8;
    const u16* ag0 = A  + (size_t)(m0 + sr)      * lda + sk;
    const u16* ag1 = A  + (size_t)(m0 + sr + 16) * lda + sk;
    const u16* bg0 = Bt + (size_t)(n0 + sr)      * K + sk;
    const u16* bg1 = Bt + (size_t)(n0 + sr + 16) * K + sk;
    u16* al0 = As + (w * 2 + 0) * 512;
    u16* al1 = As + (w * 2 + 1) * 512;
    u16* bl0 = Bs + (w * 2 + 0) * 512;
    u16* bl1 = Bs + (w * 2 + 1) * 512;

    int wm = (w >> 1) * 64, wn = (w & 1) * 64;
    int fr = lane & 15;
    int fk = (lane >> 4) * 8;

    floatx4 acc[4][4] = {};

    for (int k0 = 0; k0 < K; k0 += 32) {
        gload16(ag0 + k0, al0);
        gload16(ag1 + k0, al1);
        gload16(bg0 + k0, bl0);
        gload16(bg1 + k0, bl1);
        __syncthreads();

        short8 af[4], bf[4];
#pragma unroll
        for (int i = 0; i < 4; ++i)
            af[i] = *(const short8*)&As[(wm + i * 16 + fr) * 32 + fk];
#pragma unroll
        for (int j = 0; j < 4; ++j)
            bf[j] = *(const short8*)&Bs[(wn + j * 16 + fr) * 32 + fk];
#pragma unroll
        for (int i = 0; i < 4; ++i)
#pragma unroll
            for (int j = 0; j < 4; ++j)
                acc[i][j] = __builtin_amdgcn_mfma_f32_16x16x32_bf16(
                    af[i], bf[j], acc[i][j], 0, 0, 0);
        __syncthreads();
    }

    // epilogue: bias+relu+bf16, bounce through LDS for coalesced stores.
    // C/D frag layout: col=lane&15, row=(lane>>4)*4+reg
    u16* epi = smem + w * 4608;        // 64 rows x 72 u16 stride
    int cc = lane & 15;
    int rq = (lane >> 4) * 4;
#pragma unroll
    for (int j = 0; j < 4; ++j) {
        float bj = bias[n0 + wn + j * 16 + cc];
#pragma unroll
        for (int i = 0; i < 4; ++i) {
#pragma unroll
            for (int r = 0; r < 4; ++r) {
                float vv = acc[i][j][r] + bj;
                if (relu) vv = fmaxf(vv, 0.f);
                epi[(i * 16 + rq + r) * 72 + j * 16 + cc] = f2bf(vv);
            }
        }
    }
    __syncthreads();
#pragma unroll
    for (int t = 0; t < 8; ++t) {
        int er = t * 8 + (lane >> 3);
        int ec = (lane & 7) * 8;
        short8 vv = *(const short8*)&epi[er * 72 + ec];
        *(short8*)&C[(size_t)(m0 + wm + er) * ldc + n0 + wn + ec] = vv;
    }
}

// ---------------------------------------------------------------------------
// Flash-style attention, bf16 io, fp32 compute, strided (works on slices of
// fused QKV buffers), IN-PLACE capable (O aliases Q slice). One block =
// (b, h, 16-query tile); 64-key tiles; in-reg shfl softmax reductions.
// ---------------------------------------------------------------------------
#define QB 16
#define KB 64

__global__ __launch_bounds__(256) void attn_kernel(
    const u16* Q, int qs, const u16* __restrict__ K, int ks,
    const u16* __restrict__ V, u16* O,
    int Sq, int Sk, int causal)
{
    __shared__ __align__(16) float Qs[QB][68];
    __shared__ __align__(16) float Ks[KB][68];
    __shared__ __align__(16) float Vs[KB][68];
    __shared__ float Ps[QB][68];

    int tid = threadIdx.x;
    int qi = tid >> 4;
    int ci = tid & 15;
    int q0 = blockIdx.x * QB;
    int hh = blockIdx.y;
    int bb = blockIdx.z;

    const u16* Qb = Q + (size_t)bb * Sq * qs + hh * DH_;
    const u16* Kb = K + (size_t)bb * Sk * ks + hh * DH_;
    const u16* Vb = V + (size_t)bb * Sk * ks + hh * DH_;

    for (int idx = tid; idx < QB * DH_ / 2; idx += 256) {
        int r = idx >> 5, c2 = (idx & 31) * 2;
        int qg = q0 + r;
        if (qg < Sq) {
            unsigned qq = *(const unsigned*)&Qb[(size_t)qg * qs + c2];
            Qs[r][c2] = bf2f(qq & 0xffff); Qs[r][c2 + 1] = bf2f(qq >> 16);
        } else { Qs[r][c2] = 0.f; Qs[r][c2 + 1] = 0.f; }
    }
    float m_i = -1e30f, l_i = 0.f;
    float acc0 = 0.f, acc1 = 0.f, acc2 = 0.f, acc3 = 0.f;
    __syncthreads();

    int qg = q0 + qi;
    int kend = causal ? ((Sk < q0 + QB) ? Sk : (q0 + QB)) : Sk;
    for (int k0 = 0; k0 < kend; k0 += KB) {
        for (int idx = tid; idx < KB * DH_ / 2; idx += 256) {
            int r = idx >> 5, c2 = (idx & 31) * 2;
            int kg = k0 + r;
            if (kg < Sk) {
                unsigned kk = *(const unsigned*)&Kb[(size_t)kg * ks + c2];
                unsigned vv = *(const unsigned*)&Vb[(size_t)kg * ks + c2];
                Ks[r][c2] = bf2f(kk & 0xffff); Ks[r][c2 + 1] = bf2f(kk >> 16);
                Vs[r][c2] = bf2f(vv & 0xffff); Vs[r][c2 + 1] = bf2f(vv >> 16);
            } else {
                Ks[r][c2] = 0.f; Ks[r][c2 + 1] = 0.f;
                Vs[r][c2] = 0.f; Vs[r][c2 + 1] = 0.f;
            }
        }
        __syncthreads();

        // scores: thread (qi,ci) handles keys ci, ci+16, ci+32, ci+48
        float s0 = 0.f, s1 = 0.f, s2 = 0.f, s3 = 0.f;
#pragma unroll
        for (int dc = 0; dc < DH_; dc += 4) {
            float4 q4 = *(const float4*)&Qs[qi][dc];
            float4 k0v = *(const float4*)&Ks[ci][dc];
            float4 k1v = *(const float4*)&Ks[ci + 16][dc];
            float4 k2v = *(const float4*)&Ks[ci + 32][dc];
            float4 k3v = *(const float4*)&Ks[ci + 48][dc];
            s0 += q4.x * k0v.x + q4.y * k0v.y + q4.z * k0v.z + q4.w * k0v.w;
            s1 += q4.x * k1v.x + q4.y * k1v.y + q4.z * k1v.z + q4.w * k1v.w;
            s2 += q4.x * k2v.x + q4.y * k2v.y + q4.z * k2v.z + q4.w * k2v.w;
            s3 += q4.x * k3v.x + q4.y * k3v.y + q4.z * k3v.z + q4.w * k3v.w;
        }
        {
            int kg0 = k0 + ci, kg1 = k0 + ci + 16, kg2 = k0 + ci + 32, kg3 = k0 + ci + 48;
            s0 = (kg0 >= Sk || (causal && kg0 > qg)) ? -1e9f : s0 * 0.125f;
            s1 = (kg1 >= Sk || (causal && kg1 > qg)) ? -1e9f : s1 * 0.125f;
            s2 = (kg2 >= Sk || (causal && kg2 > qg)) ? -1e9f : s2 * 0.125f;
            s3 = (kg3 >= Sk || (causal && kg3 > qg)) ? -1e9f : s3 * 0.125f;
        }
        // row max across the 16 lanes sharing this query row (in-wave)
        float mx = fmaxf(fmaxf(s0, s1), fmaxf(s2, s3));
#pragma unroll
        for (int off = 1; off < 16; off <<= 1)
            mx = fmaxf(mx, __shfl_xor(mx, off, 16));
        float mnew = fmaxf(m_i, mx);
        float alpha = expf(m_i - mnew);
        float p0 = expf(s0 - mnew), p1 = expf(s1 - mnew);
        float p2 = expf(s2 - mnew), p3 = expf(s3 - mnew);
        float ps = p0 + p1 + p2 + p3;
#pragma unroll
        for (int off = 1; off < 16; off <<= 1)
            ps += __shfl_xor(ps, off, 16);
        l_i = l_i * alpha + ps;
        m_i = mnew;
        acc0 *= alpha; acc1 *= alpha; acc2 *= alpha; acc3 *= alpha;
        Ps[qi][ci] = p0; Ps[qi][ci + 16] = p1;
        Ps[qi][ci + 32] = p2; Ps[qi][ci + 48] = p3;
        __syncthreads();

#pragma unroll
        for (int kj = 0; kj < KB; ++kj) {
            float p = Ps[qi][kj];
            float4 v4 = *(const float4*)&Vs[kj][ci * 4];
            acc0 = fmaf(p, v4.x, acc0);
            acc1 = fmaf(p, v4.y, acc1);
            acc2 = fmaf(p, v4.z, acc2);
            acc3 = fmaf(p, v4.w, acc3);
        }
        __syncthreads();
    }

    if (qg < Sq) {
        float inv = 1.0f / l_i;
        u16* Op = O + (size_t)bb * Sq * qs + (size_t)qg * qs + hh * DH_ + ci * 4;
        Op[0] = f2bf(acc0 * inv); Op[1] = f2bf(acc1 * inv);
        Op[2] = f2bf(acc2 * inv); Op[3] = f2bf(acc3 * inv);
    }
}

// ---------------------------------------------------------------------------
// h[row,:] = LN(h[row,:] + delta[row,:]) * scale + bias (bf16 io, fp32 math)
// 128 threads, single barrier (wave shfl reduction, E[x^2]-mu^2 variance).
// ---------------------------------------------------------------------------
__global__ __launch_bounds__(128) void add_ln_kernel(
    u16* __restrict__ h, const u16* __restrict__ delta,
    const float* __restrict__ scale, const float* __restrict__ bias)
{
    __shared__ float red[2][2];
    int row = blockIdx.x, tid = threadIdx.x;
    int lane = tid & 63, wv = tid >> 6;
    size_t base = (size_t)row * D_ + tid * 4;
    uint2 hv = *(const uint2*)&h[base];
    uint2 dv = *(const uint2*)&delta[base];
    float v0 = bf2f(hv.x & 0xffff) + bf2f(dv.x & 0xffff);
    float v1 = bf2f(hv.x >> 16)    + bf2f(dv.x >> 16);
    float v2 = bf2f(hv.y & 0xffff) + bf2f(dv.y & 0xffff);
    float v3 = bf2f(hv.y >> 16)    + bf2f(dv.y >> 16);

    float a  = v0 + v1 + v2 + v3;
    float b2 = v0 * v0 + v1 * v1 + v2 * v2 + v3 * v3;
#pragma unroll
    for (int off = 32; off > 0; off >>= 1) {
        a  += __shfl_xor(a, off);
        b2 += __shfl_xor(b2, off);
    }
    if (lane == 0) { red[wv][0] = a; red[wv][1] = b2; }
    __syncthreads();
    float S1 = red[0][0] + red[1][0];
    float S2 = red[0][1] + red[1][1];
    float mu = S1 * (1.0f / 512.0f);
    float var = S2 * (1.0f / 512.0f) - mu * mu;
    float rs = rsqrtf(var + 1e-5f);

    int c = tid * 4;
    float4 sc = *(const float4*)&scale[c];
    float4 bi = *(const float4*)&bias[c];
    unsigned lo = (unsigned)f2bf((v0 - mu) * rs * sc.x + bi.x) |
                  ((unsigned)f2bf((v1 - mu) * rs * sc.y + bi.y) << 16);
    unsigned hi = (unsigned)f2bf((v2 - mu) * rs * sc.z + bi.z) |
                  ((unsigned)f2bf((v3 - mu) * rs * sc.w + bi.w) << 16);
    *(uint2*)&h[base] = make_uint2(lo, hi);
}

// ---------------------------------------------------------------------------
// out[row] = d[row,:] . w[:] + b   (one wave per row; d bf16, out fp32)
// ---------------------------------------------------------------------------
__global__ __launch_bounds__(64) void out_proj_kernel(
    const u16* __restrict__ d, const float* __restrict__ w,
    const float* __restrict__ b, float* __restrict__ out)
{
    int row = blockIdx.x, lane = threadIdx.x;
    float s = 0.f;
    for (int c = lane; c < D_; c += 64) s += bf2f(d[(size_t)row * D_ + c]) * w[c];
#pragma unroll
    for (int off = 32; off > 0; off >>= 1) s += __shfl_down(s, off);
    if (lane == 0) out[row] = s + b[0];
}

// ---------------------------------------------------------------------------
// Host orchestration
// ---------------------------------------------------------------------------
extern "C" void kernel_launch(void* const* d_in, const int* in_sizes, int n_in,
                              void* d_out, int out_size, void* d_ws, size_t ws_size,
                              hipStream_t stream)
{
    const float* x          = (const float*)d_in[0];
    const float* y          = (const float*)d_in[1];
    const float* src_w      = (const float*)d_in[2];
    const float* src_b      = (const float*)d_in[3];
    const float* tgt_w      = (const float*)d_in[4];
    const float* tgt_b      = (const float*)d_in[5];
    const float* enc_attn_w = (const float*)d_in[6];
    const float* enc_attn_b = (const float*)d_in[7];
    const float* enc_ffn_w1 = (const float*)d_in[8];
    const float* enc_ffn_b1 = (const float*)d_in[9];
    const float* enc_ffn_w2 = (const float*)d_in[10];
    const float* enc_ffn_b2 = (const float*)d_in[11];
    const float* enc_ln_s   = (const float*)d_in[12];
    const float* enc_ln_b   = (const float*)d_in[13];
    const float* dec_self_w = (const float*)d_in[14];
    const float* dec_self_b = (const float*)d_in[15];
    const float* dec_cross_w= (const float*)d_in[16];
    const float* dec_cross_b= (const float*)d_in[17];
    const float* dec_ffn_w1 = (const float*)d_in[18];
    const float* dec_ffn_b1 = (const float*)d_in[19];
    const float* dec_ffn_w2 = (const float*)d_in[20];
    const float* dec_ffn_b2 = (const float*)d_in[21];
    const float* dec_ln_s   = (const float*)d_in[22];
    const float* dec_ln_b   = (const float*)d_in[23];
    const float* out_w      = (const float*)d_in[24];
    const float* out_b      = (const float*)d_in[25];
    float* out = (float*)d_out;

    // Workspace (u16 elems). Total = 49,086,464 u16 = 98.2 MB.
    const size_t E_BSD = (size_t)B_ * S_ * D_;    // 8,388,608
    const size_t E_BTD = (size_t)B_ * T_ * D_;    // 2,949,120
    const size_t WDD   = (size_t)D_ * D_;         // 262,144
    const size_t WDF   = (size_t)D_ * F_;         // 1,048,576
    const int MS = B_ * S_;   // 16384
    const int MT = B_ * T_;   // 5760

    u16* h    = (u16*)d_ws;                  // encoder state -> memory
    u16* qkv  = h + E_BSD;                   // [MS,1536] fused QKV / scratch
    u16* o    = qkv + (size_t)MS * 1536;     // [MS,512] proj/FFN output
    u16* dbuf = o + E_BSD;                   // decoder state
    u16* wsc  = dbuf + E_BTD;                // weight scratch (10 slots max)
    // aliases into qkv region (dead when used):
    u16* mid  = qkv;                         // FFN hidden (<= 8192x2048)
    u16* cq   = qkv;                         // cross-attn Q [MT,512]
    u16* ckv  = qkv + 4 * 1024 * 1024;       // cross-attn KV [MS,1024]

    auto gemm = [&](const u16* A, int lda, const u16* Wt, const float* bi,
                    u16* C, int ldc, int M, int N, int K, int relu) {
        dim3 g(N / 128, M / 128);
        gemm_bf16_kernel<<<g, dim3(256), 0, stream>>>(A, lda, Wt, bi, C, ldc,
                                                      M, N, K, relu);
    };
    auto attn = [&](const u16* Qp, int qs, const u16* Kp, int ks,
                    const u16* Vp, u16* Op, int Sq, int Sk, int causal) {
        dim3 g((Sq + QB - 1) / QB, H_, B_);
        attn_kernel<<<g, dim3(256), 0, stream>>>(Qp, qs, Kp, ks, Vp, Op,
                                                 Sq, Sk, causal);
    };
    auto addln = [&](u16* hp, const u16* dp, const float* sc, const float* bi,
                     int rows) {
        add_ln_kernel<<<dim3(rows), dim3(128), 0, stream>>>(hp, dp, sc, bi);
    };
    auto wconv = [&](const float* W, u16* Wt, int K, int N, int nmat) {
        wconv_kernel<<<dim3(N / 32, K / 32, nmat), dim3(256), 0, stream>>>(W, Wt, K, N);
    };

    // ---- encoder ----
    embed_src_kernel<<<dim3((B_ * S_ * D_ + 255) / 256), dim3(256), 0, stream>>>(
        x, src_w, src_b, h);
    for (int l = 0; l < L_; ++l) {
        wconv(enc_attn_w + (size_t)l * 4 * WDD, wsc, D_, D_, 4);   // q,k,v,o
        wconv(enc_ffn_w1 + (size_t)l * WDF, wsc + 4 * WDD, D_, F_, 1);
        wconv(enc_ffn_w2 + (size_t)l * WDF, wsc + 4 * WDD + WDF, F_, D_, 1);

        const float* bl = enc_attn_b + (size_t)l * 4 * D_;
        // fused QKV: N=1536, bias [bq|bk|bv] contiguous
        gemm(h, D_, wsc, bl, qkv, 1536, MS, 1536, D_, 0);
        attn(qkv, 1536, qkv + 512, 1536, qkv + 1024, qkv, S_, S_, 0); // in-place
        gemm(qkv, 1536, wsc + 3 * WDD, bl + 3 * D_, o, D_, MS, D_, D_, 0);
        addln(h, o, enc_ln_s + (size_t)l * 2 * D_, enc_ln_b + (size_t)l * 2 * D_, MS);

        // FFN, chunked by 8192 rows (mid aliases dead qkv region)
        for (int m0 = 0; m0 < MS; m0 += 8192) {
            gemm(h + (size_t)m0 * D_, D_, wsc + 4 * WDD,
                 enc_ffn_b1 + (size_t)l * F_, mid, F_, 8192, F_, D_, 1);
            gemm(mid, F_, wsc + 4 * WDD + WDF, enc_ffn_b2 + (size_t)l * D_,
                 o + (size_t)m0 * D_, D_, 8192, D_, F_, 0);
        }
        addln(h, o, enc_ln_s + (size_t)l * 2 * D_ + D_,
              enc_ln_b + (size_t)l * 2 * D_ + D_, MS);
    }
    // h == memory from here on.

    // ---- decoder ----
    embed_tgt_kernel<<<dim3((B_ * T_ * D_ + 255) / 256), dim3(256), 0, stream>>>(
        y, tgt_w, tgt_b, dbuf);
    for (int l = 0; l < L_; ++l) {
        wconv(dec_self_w  + (size_t)l * 4 * WDD, wsc, D_, D_, 4);
        wconv(dec_cross_w + (size_t)l * 4 * WDD, wsc + 4 * WDD, D_, D_, 4);
        wconv(dec_ffn_w1  + (size_t)l * WDF, wsc + 8 * WDD, D_, F_, 1);
        wconv(dec_ffn_w2  + (size_t)l * WDF, wsc + 8 * WDD + WDF, F_, D_, 1);

        // self-attention (causal), fused QKV
        const float* bl = dec_self_b + (size_t)l * 4 * D_;
        gemm(dbuf, D_, wsc, bl, qkv, 1536, MT, 1536, D_, 0);
        attn(qkv, 1536, qkv + 512, 1536, qkv + 1024, qkv, T_, T_, 1);
        gemm(qkv, 1536, wsc + 3 * WDD, bl + 3 * D_, o, D_, MT, D_, D_, 0);
        addln(dbuf, o, dec_ln_s + (size_t)l * 3 * D_,
              dec_ln_b + (size_t)l * 3 * D_, MT);

        // cross-attention: fused KV over memory, Q over decoder state
        const float* bc = dec_cross_b + (size_t)l * 4 * D_;
        gemm(h, D_, wsc + 5 * WDD, bc + D_, ckv, 1024, MS, 1024, D_, 0);
        gemm(dbuf, D_, wsc + 4 * WDD, bc, cq, D_, MT, D_, D_, 0);
        attn(cq, 512, ckv, 1024, ckv + 512, cq, T_, S_, 0);   // in-place
        gemm(cq, D_, wsc + 7 * WDD, bc + 3 * D_, o, D_, MT, D_, D_, 0);
        addln(dbuf, o, dec_ln_s + (size_t)l * 3 * D_ + D_,
              dec_ln_b + (size_t)l * 3 * D_ + D_, MT);

        // FFN (single chunk, MT=5760 rows)
        gemm(dbuf, D_, wsc + 8 * WDD, dec_ffn_b1 + (size_t)l * F_,
             mid, F_, MT, F_, D_, 1);
        gemm(mid, F_, wsc + 8 * WDD + WDF, dec_ffn_b2 + (size_t)l * D_,
             o, D_, MT, D_, F_, 0);
        addln(dbuf, o, dec_ln_s + (size_t)l * 3 * D_ + 2 * D_,
              dec_ln_b + (size_t)l * 3 * D_ + 2 * D_, MT);
    }

    out_proj_kernel<<<dim3(MT), dim3(64), 0, stream>>>(dbuf, out_w, out_b, out);
}

// Round 5
// 3769.371 us; speedup vs baseline: 6.4945x; 2.1707x over previous
//
#include <hip/hip_runtime.h>
#include <math.h>

// Problem constants (TransformerController)
#define B_  32
#define S_  512
#define T_  180
#define D_  512
#define F_  2048
#define L_  6
#define H_  8
#define DH_ 64

typedef unsigned short u16;
typedef __attribute__((ext_vector_type(8))) short short8;   // 8 x bf16
typedef __attribute__((ext_vector_type(4))) float floatx4;  // MFMA acc

__device__ __forceinline__ float bf2f(u16 h) {
    union { unsigned u; float f; } un; un.u = ((unsigned)h) << 16; return un.f;
}
__device__ __forceinline__ u16 f2bf(float f) {
    union { float f; unsigned u; } un; un.f = f;
    unsigned u = un.u;
    u += 0x7fffu + ((u >> 16) & 1u);   // RNE
    return (u16)(u >> 16);
}

// async global->LDS, 16B per lane, dest = wave-uniform base + lane*16
__device__ __forceinline__ void gload16(const u16* g, u16* l) {
    __builtin_amdgcn_global_load_lds(
        (const __attribute__((address_space(1))) void*)g,
        (__attribute__((address_space(3))) void*)l, 16, 0, 0);
}

// ---------------------------------------------------------------------------
// Embedding kernels -> bf16
// ---------------------------------------------------------------------------
__device__ __forceinline__ float pos_enc(int pos, int c) {
    int i2 = c & ~1;
    float div = expf(-(float)i2 * (9.210340371976184f / 512.0f));
    float arg = (float)pos * div;
    return (c & 1) ? cosf(arg) : sinf(arg);
}

__global__ __launch_bounds__(256) void embed_src_kernel(
    const float* __restrict__ x, const float* __restrict__ w,
    const float* __restrict__ b, u16* __restrict__ h)
{
    int idx = blockIdx.x * 256 + threadIdx.x;
    if (idx >= B_ * S_ * D_) return;
    int c  = idx & (D_ - 1);
    int bs = idx >> 9;
    int s  = bs & (S_ - 1);
    float x0 = x[bs * 2 + 0];
    float x1 = x[bs * 2 + 1];
    h[idx] = f2bf(x0 * w[c] + x1 * w[D_ + c] + b[c] + pos_enc(s, c));
}

__global__ __launch_bounds__(256) void embed_tgt_kernel(
    const float* __restrict__ y, const float* __restrict__ w,
    const float* __restrict__ b, u16* __restrict__ d)
{
    int idx = blockIdx.x * 256 + threadIdx.x;
    if (idx >= B_ * T_ * D_) return;
    int c  = idx & (D_ - 1);
    int bt = idx >> 9;
    int t  = bt % T_;
    int bb = bt / T_;
    float tv = (t == 0) ? 0.0f : y[bb * T_ + (t - 1)];
    d[idx] = f2bf(tv * w[c] + b[c] + pos_enc(t, c));
}

// ---------------------------------------------------------------------------
// Weight convert+transpose: W[K,N] fp32 -> Wt[N,K] bf16. blockIdx.z = matrix.
// ---------------------------------------------------------------------------
__global__ __launch_bounds__(256) void wconv_kernel(
    const float* __restrict__ W, u16* __restrict__ Wt, int K, int N)
{
    __shared__ float tile[32][33];
    size_t mat = (size_t)blockIdx.z * K * N;
    const float* Wm = W + mat;
    u16* Wtm = Wt + mat;
    int n0 = blockIdx.x * 32, k0 = blockIdx.y * 32;
    int tx = threadIdx.x & 31, ty = threadIdx.x >> 5;   // ty 0..7
#pragma unroll
    for (int i = 0; i < 32; i += 8)
        tile[ty + i][tx] = Wm[(size_t)(k0 + ty + i) * N + n0 + tx];
    __syncthreads();
#pragma unroll
    for (int i = 0; i < 32; i += 8)
        Wtm[(size_t)(n0 + ty + i) * K + k0 + tx] = f2bf(tile[tx][ty + i]);
}

// ---------------------------------------------------------------------------
// bf16 MFMA GEMM: C[M,N] = act(A[M,K](lda) @ Wt[N,K]^T + bias), bf16 io,
// fp32 acc. 128x128 tile, BK=32, 256 thr (4 waves, 2x2 of 64x64 quadrants).
// M,N mult of 128; K mult of 32. LDS-bounce epilogue -> coalesced 16B stores.
// ---------------------------------------------------------------------------
__global__ __launch_bounds__(256) void gemm_bf16_kernel(
    const u16* __restrict__ A, int lda, const u16* __restrict__ Bt,
    const float* __restrict__ bias, u16* __restrict__ C, int ldc,
    int M, int N, int K, int relu)
{
    // As/Bs: 128x32 each (8 KB each). epi: 4 waves x 64 rows x 72 u16 = 36 KB.
    __shared__ u16 smem[18432];
    u16* As = smem;
    u16* Bs = smem + 4096;

    int tid  = threadIdx.x;
    int w    = tid >> 6;
    int lane = tid & 63;
    int m0 = blockIdx.y << 7, n0 = blockIdx.x << 7;

    // staging: per wave 2 instrs for A, 2 for B; 16 rows/instr, 4 lanes/row
    int sr = w * 32 + (lane >> 2);
    int sk = (lane & 3) * 8;
    const u16* ag0 = A  + (size_t)(m0 + sr)      * lda + sk;
    const u16* ag1 = A  + (size_t)(m0 + sr + 16) * lda + sk;
    const u16* bg0 = Bt + (size_t)(n0 + sr)      * K + sk;
    const u16* bg1 = Bt + (size_t)(n0 + sr + 16) * K + sk;
    u16* al0 = As + (w * 2 + 0) * 512;
    u16* al1 = As + (w * 2 + 1) * 512;
    u16* bl0 = Bs + (w * 2 + 0) * 512;
    u16* bl1 = Bs + (w * 2 + 1) * 512;

    int wm = (w >> 1) * 64, wn = (w & 1) * 64;
    int fr = lane & 15;
    int fk = (lane >> 4) * 8;

    floatx4 acc[4][4] = {};

    for (int k0 = 0; k0 < K; k0 += 32) {
        gload16(ag0 + k0, al0);
        gload16(ag1 + k0, al1);
        gload16(bg0 + k0, bl0);
        gload16(bg1 + k0, bl1);
        __syncthreads();

        short8 af[4], bf[4];
#pragma unroll
        for (int i = 0; i < 4; ++i)
            af[i] = *(const short8*)&As[(wm + i * 16 + fr) * 32 + fk];
#pragma unroll
        for (int j = 0; j < 4; ++j)
            bf[j] = *(const short8*)&Bs[(wn + j * 16 + fr) * 32 + fk];
#pragma unroll
        for (int i = 0; i < 4; ++i)
#pragma unroll
            for (int j = 0; j < 4; ++j)
                acc[i][j] = __builtin_amdgcn_mfma_f32_16x16x32_bf16(
                    af[i], bf[j], acc[i][j], 0, 0, 0);
        __syncthreads();
    }

    // epilogue: bias+relu+bf16, bounce through LDS for coalesced stores.
    // C/D frag layout: col=lane&15, row=(lane>>4)*4+reg
    u16* epi = smem + w * 4608;        // 64 rows x 72 u16 stride
    int cc = lane & 15;
    int rq = (lane >> 4) * 4;
#pragma unroll
    for (int j = 0; j < 4; ++j) {
        float bj = bias[n0 + wn + j * 16 + cc];
#pragma unroll
        for (int i = 0; i < 4; ++i) {
#pragma unroll
            for (int r = 0; r < 4; ++r) {
                float vv = acc[i][j][r] + bj;
                if (relu) vv = fmaxf(vv, 0.f);
                epi[(i * 16 + rq + r) * 72 + j * 16 + cc] = f2bf(vv);
            }
        }
    }
    __syncthreads();
#pragma unroll
    for (int t = 0; t < 8; ++t) {
        int er = t * 8 + (lane >> 3);
        int ec = (lane & 7) * 8;
        short8 vv = *(const short8*)&epi[er * 72 + ec];
        *(short8*)&C[(size_t)(m0 + wm + er) * ldc + n0 + wn + ec] = vv;
    }
}

// ---------------------------------------------------------------------------
// MFMA flash attention, bf16 io, fp32 softmax/acc. Strided (slices of fused
// QKV buffers), IN-PLACE capable (O aliases Q slice; block writes only its
// own rows x head-cols). One block = (b, h, 64-query tile): 4 waves x 16 q.
// 64-key tiles. QK^T and PV on matrix cores; P via per-wave LDS round-trip;
// V^T staged with rotated columns (conflict-free transpose + b128 reads).
// ---------------------------------------------------------------------------
__global__ __launch_bounds__(256) void attn_mfma_kernel(
    const u16* Q, int qs, const u16* __restrict__ K, int ks,
    const u16* __restrict__ V, u16* O,
    int Sq, int Sk, int causal)
{
    __shared__ u16 Qs[64 * 72];      // [qrow][d], row-major, stride 72
    __shared__ u16 Ks[64 * 72];      // [key][d]
    __shared__ u16 Vt[64 * 72];      // [d][(k + (d&~7)) & 63]  (rotated cols)
    __shared__ u16 Ps[4][16 * 72];   // per-wave P tile [q][key]

    int tid  = threadIdx.x;
    int w    = tid >> 6;
    int lane = tid & 63;
    int n    = lane & 15;
    int quad = lane >> 4;
    int q0 = blockIdx.x * 64;
    int hh = blockIdx.y, bb = blockIdx.z;

    const u16* Qb = Q + (size_t)bb * Sq * qs + hh * DH_;
    const u16* Kb = K + (size_t)bb * Sk * ks + hh * DH_;
    const u16* Vb = V + (size_t)bb * Sk * ks + hh * DH_;

    // ---- stage Q once: 64 rows x 64 d ----
#pragma unroll
    for (int it = 0; it < 2; ++it) {
        int idx = it * 256 + tid;          // 0..511
        int r = idx >> 3, dg = (idx & 7) * 8;
        int qg = q0 + r;
        short8 vv = {};
        if (qg < Sq) vv = *(const short8*)&Qb[(size_t)qg * qs + dg];
        *(short8*)&Qs[r * 72 + dg] = vv;
    }

    float m_i[4], l_i[4];
    floatx4 o_acc[4] = {};
#pragma unroll
    for (int r = 0; r < 4; ++r) { m_i[r] = -1e30f; l_i[r] = 0.f; }

    int qrow0 = q0 + w * 16 + quad * 4;    // this lane's 4 q-rows
    int kend = causal ? ((Sk < q0 + 64) ? Sk : (q0 + 64)) : Sk;
    __syncthreads();

    for (int k0 = 0; k0 < kend; k0 += 64) {
        // ---- stage K (row-major) and V (transposed, rotated cols) ----
#pragma unroll
        for (int it = 0; it < 2; ++it) {
            int idx = it * 256 + tid;
            int r = idx >> 3, dg = (idx & 7) * 8;
            int kg = k0 + r;
            short8 kv = {}, vv = {};
            if (kg < Sk) {
                kv = *(const short8*)&Kb[(size_t)kg * ks + dg];
                vv = *(const short8*)&Vb[(size_t)kg * ks + dg];
            }
            *(short8*)&Ks[r * 72 + dg] = kv;
            int col = (r + dg) & 63;       // rotation: rot(d) = d & ~7 = dg
#pragma unroll
            for (int j = 0; j < 8; ++j)
                Vt[(dg + j) * 72 + col] = (u16)vv[j];
        }
        __syncthreads();

        // ---- QK^T: S-tile 16q x 64k in C-layout frags ----
        floatx4 sc[4] = {};
        short8 aq0 = *(const short8*)&Qs[(w * 16 + n) * 72 + quad * 8];
        short8 aq1 = *(const short8*)&Qs[(w * 16 + n) * 72 + 32 + quad * 8];
#pragma unroll
        for (int j = 0; j < 4; ++j) {
            short8 bk0 = *(const short8*)&Ks[(j * 16 + n) * 72 + quad * 8];
            short8 bk1 = *(const short8*)&Ks[(j * 16 + n) * 72 + 32 + quad * 8];
            sc[j] = __builtin_amdgcn_mfma_f32_16x16x32_bf16(aq0, bk0, sc[j], 0, 0, 0);
            sc[j] = __builtin_amdgcn_mfma_f32_16x16x32_bf16(aq1, bk1, sc[j], 0, 0, 0);
        }

        // ---- mask + scale ----
#pragma unroll
        for (int j = 0; j < 4; ++j) {
            int kg = k0 + j * 16 + n;
#pragma unroll
            for (int r = 0; r < 4; ++r) {
                float s = sc[j][r] * 0.125f;
                if (kg >= Sk || (causal && kg > qrow0 + r)) s = -1e9f;
                sc[j][r] = s;
            }
        }

        // ---- online softmax (in-register, width-16 shfl rows) ----
#pragma unroll
        for (int r = 0; r < 4; ++r) {
            float mx = fmaxf(fmaxf(sc[0][r], sc[1][r]), fmaxf(sc[2][r], sc[3][r]));
#pragma unroll
            for (int off = 8; off > 0; off >>= 1)
                mx = fmaxf(mx, __shfl_xor(mx, off, 16));
            float mnew = fmaxf(m_i[r], mx);
            float alpha = __expf(m_i[r] - mnew);
            m_i[r] = mnew;
            float ps = 0.f;
#pragma unroll
            for (int j = 0; j < 4; ++j) {
                float p = __expf(sc[j][r] - mnew);
                sc[j][r] = p; ps += p;
            }
#pragma unroll
            for (int off = 8; off > 0; off >>= 1)
                ps += __shfl_xor(ps, off, 16);
            l_i[r] = l_i[r] * alpha + ps;
#pragma unroll
            for (int jb = 0; jb < 4; ++jb) o_acc[jb][r] *= alpha;
        }

        // ---- P: C-layout regs -> per-wave LDS [q][key] ----
#pragma unroll
        for (int j = 0; j < 4; ++j)
#pragma unroll
            for (int r = 0; r < 4; ++r)
                Ps[w][(quad * 4 + r) * 72 + j * 16 + n] = f2bf(sc[j][r]);

        // ---- PV: A = P (LDS, A-layout), B = V^T (rotated) ----
        short8 ap0 = *(const short8*)&Ps[w][n * 72 + quad * 8];
        short8 ap1 = *(const short8*)&Ps[w][n * 72 + 32 + quad * 8];
#pragma unroll
        for (int jb = 0; jb < 4; ++jb) {
            int d = jb * 16 + n;
            int rot = d & ~7;
            short8 bv0 = *(const short8*)&Vt[d * 72 + ((quad * 8 + rot) & 63)];
            short8 bv1 = *(const short8*)&Vt[d * 72 + ((32 + quad * 8 + rot) & 63)];
            o_acc[jb] = __builtin_amdgcn_mfma_f32_16x16x32_bf16(ap0, bv0, o_acc[jb], 0, 0, 0);
            o_acc[jb] = __builtin_amdgcn_mfma_f32_16x16x32_bf16(ap1, bv1, o_acc[jb], 0, 0, 0);
        }
        __syncthreads();
    }

    // ---- output: O[q][d], C-layout frags ----
    float inv[4];
#pragma unroll
    for (int r = 0; r < 4; ++r) inv[r] = 1.0f / l_i[r];
    u16* Ob = O + (size_t)bb * Sq * qs + hh * DH_;
#pragma unroll
    for (int r = 0; r < 4; ++r) {
        int qg = qrow0 + r;
        if (qg < Sq) {
#pragma unroll
            for (int jb = 0; jb < 4; ++jb)
                Ob[(size_t)qg * qs + jb * 16 + n] = f2bf(o_acc[jb][r] * inv[r]);
        }
    }
}

// ---------------------------------------------------------------------------
// h[row,:] = LN(h[row,:] + delta[row,:]) * scale + bias (bf16 io, fp32 math)
// 128 threads, single barrier (wave shfl reduction, E[x^2]-mu^2 variance).
// ---------------------------------------------------------------------------
__global__ __launch_bounds__(128) void add_ln_kernel(
    u16* __restrict__ h, const u16* __restrict__ delta,
    const float* __restrict__ scale, const float* __restrict__ bias)
{
    __shared__ float red[2][2];
    int row = blockIdx.x, tid = threadIdx.x;
    int lane = tid & 63, wv = tid >> 6;
    size_t base = (size_t)row * D_ + tid * 4;
    uint2 hv = *(const uint2*)&h[base];
    uint2 dv = *(const uint2*)&delta[base];
    float v0 = bf2f(hv.x & 0xffff) + bf2f(dv.x & 0xffff);
    float v1 = bf2f(hv.x >> 16)    + bf2f(dv.x >> 16);
    float v2 = bf2f(hv.y & 0xffff) + bf2f(dv.y & 0xffff);
    float v3 = bf2f(hv.y >> 16)    + bf2f(dv.y >> 16);

    float a  = v0 + v1 + v2 + v3;
    float b2 = v0 * v0 + v1 * v1 + v2 * v2 + v3 * v3;
#pragma unroll
    for (int off = 32; off > 0; off >>= 1) {
        a  += __shfl_xor(a, off);
        b2 += __shfl_xor(b2, off);
    }
    if (lane == 0) { red[wv][0] = a; red[wv][1] = b2; }
    __syncthreads();
    float S1 = red[0][0] + red[1][0];
    float S2 = red[0][1] + red[1][1];
    float mu = S1 * (1.0f / 512.0f);
    float var = S2 * (1.0f / 512.0f) - mu * mu;
    float rs = rsqrtf(var + 1e-5f);

    int c = tid * 4;
    float4 sc = *(const float4*)&scale[c];
    float4 bi = *(const float4*)&bias[c];
    unsigned lo = (unsigned)f2bf((v0 - mu) * rs * sc.x + bi.x) |
                  ((unsigned)f2bf((v1 - mu) * rs * sc.y + bi.y) << 16);
    unsigned hi = (unsigned)f2bf((v2 - mu) * rs * sc.z + bi.z) |
                  ((unsigned)f2bf((v3 - mu) * rs * sc.w + bi.w) << 16);
    *(uint2*)&h[base] = make_uint2(lo, hi);
}

// ---------------------------------------------------------------------------
// out[row] = d[row,:] . w[:] + b   (one wave per row; d bf16, out fp32)
// ---------------------------------------------------------------------------
__global__ __launch_bounds__(64) void out_proj_kernel(
    const u16* __restrict__ d, const float* __restrict__ w,
    const float* __restrict__ b, float* __restrict__ out)
{
    int row = blockIdx.x, lane = threadIdx.x;
    float s = 0.f;
    for (int c = lane; c < D_; c += 64) s += bf2f(d[(size_t)row * D_ + c]) * w[c];
#pragma unroll
    for (int off = 32; off > 0; off >>= 1) s += __shfl_down(s, off);
    if (lane == 0) out[row] = s + b[0];
}

// ---------------------------------------------------------------------------
// Host orchestration
// ---------------------------------------------------------------------------
extern "C" void kernel_launch(void* const* d_in, const int* in_sizes, int n_in,
                              void* d_out, int out_size, void* d_ws, size_t ws_size,
                              hipStream_t stream)
{
    const float* x          = (const float*)d_in[0];
    const float* y          = (const float*)d_in[1];
    const float* src_w      = (const float*)d_in[2];
    const float* src_b      = (const float*)d_in[3];
    const float* tgt_w      = (const float*)d_in[4];
    const float* tgt_b      = (const float*)d_in[5];
    const float* enc_attn_w = (const float*)d_in[6];
    const float* enc_attn_b = (const float*)d_in[7];
    const float* enc_ffn_w1 = (const float*)d_in[8];
    const float* enc_ffn_b1 = (const float*)d_in[9];
    const float* enc_ffn_w2 = (const float*)d_in[10];
    const float* enc_ffn_b2 = (const float*)d_in[11];
    const float* enc_ln_s   = (const float*)d_in[12];
    const float* enc_ln_b   = (const float*)d_in[13];
    const float* dec_self_w = (const float*)d_in[14];
    const float* dec_self_b = (const float*)d_in[15];
    const float* dec_cross_w= (const float*)d_in[16];
    const float* dec_cross_b= (const float*)d_in[17];
    const float* dec_ffn_w1 = (const float*)d_in[18];
    const float* dec_ffn_b1 = (const float*)d_in[19];
    const float* dec_ffn_w2 = (const float*)d_in[20];
    const float* dec_ffn_b2 = (const float*)d_in[21];
    const float* dec_ln_s   = (const float*)d_in[22];
    const float* dec_ln_b   = (const float*)d_in[23];
    const float* out_w      = (const float*)d_in[24];
    const float* out_b      = (const float*)d_in[25];
    float* out = (float*)d_out;

    // Workspace (u16 elems). Total = 49,086,464 u16 = 98.2 MB.
    const size_t E_BSD = (size_t)B_ * S_ * D_;    // 8,388,608
    const size_t E_BTD = (size_t)B_ * T_ * D_;    // 2,949,120
    const size_t WDD   = (size_t)D_ * D_;         // 262,144
    const size_t WDF   = (size_t)D_ * F_;         // 1,048,576
    const int MS = B_ * S_;   // 16384
    const int MT = B_ * T_;   // 5760

    u16* h    = (u16*)d_ws;                  // encoder state -> memory
    u16* qkv  = h + E_BSD;                   // [MS,1536] fused QKV / scratch
    u16* o    = qkv + (size_t)MS * 1536;     // [MS,512] proj/FFN output
    u16* dbuf = o + E_BSD;                   // decoder state
    u16* wsc  = dbuf + E_BTD;                // weight scratch (10 slots max)
    // aliases into qkv region (dead when used):
    u16* mid  = qkv;                         // FFN hidden (<= 8192x2048)
    u16* cq   = qkv;                         // cross-attn Q [MT,512]
    u16* ckv  = qkv + 4 * 1024 * 1024;       // cross-attn KV [MS,1024]

    auto gemm = [&](const u16* A, int lda, const u16* Wt, const float* bi,
                    u16* C, int ldc, int M, int N, int K, int relu) {
        dim3 g(N / 128, M / 128);
        gemm_bf16_kernel<<<g, dim3(256), 0, stream>>>(A, lda, Wt, bi, C, ldc,
                                                      M, N, K, relu);
    };
    auto attn = [&](const u16* Qp, int qs, const u16* Kp, int ks,
                    const u16* Vp, u16* Op, int Sq, int Sk, int causal) {
        dim3 g((Sq + 63) / 64, H_, B_);
        attn_mfma_kernel<<<g, dim3(256), 0, stream>>>(Qp, qs, Kp, ks, Vp, Op,
                                                      Sq, Sk, causal);
    };
    auto addln = [&](u16* hp, const u16* dp, const float* sc, const float* bi,
                     int rows) {
        add_ln_kernel<<<dim3(rows), dim3(128), 0, stream>>>(hp, dp, sc, bi);
    };
    auto wconv = [&](const float* W, u16* Wt, int K, int N, int nmat) {
        wconv_kernel<<<dim3(N / 32, K / 32, nmat), dim3(256), 0, stream>>>(W, Wt, K, N);
    };

    // ---- encoder ----
    embed_src_kernel<<<dim3((B_ * S_ * D_ + 255) / 256), dim3(256), 0, stream>>>(
        x, src_w, src_b, h);
    for (int l = 0; l < L_; ++l) {
        wconv(enc_attn_w + (size_t)l * 4 * WDD, wsc, D_, D_, 4);   // q,k,v,o
        wconv(enc_ffn_w1 + (size_t)l * WDF, wsc + 4 * WDD, D_, F_, 1);
        wconv(enc_ffn_w2 + (size_t)l * WDF, wsc + 4 * WDD + WDF, F_, D_, 1);

        const float* bl = enc_attn_b + (size_t)l * 4 * D_;
        // fused QKV: N=1536, bias [bq|bk|bv] contiguous
        gemm(h, D_, wsc, bl, qkv, 1536, MS, 1536, D_, 0);
        attn(qkv, 1536, qkv + 512, 1536, qkv + 1024, qkv, S_, S_, 0); // in-place
        gemm(qkv, 1536, wsc + 3 * WDD, bl + 3 * D_, o, D_, MS, D_, D_, 0);
        addln(h, o, enc_ln_s + (size_t)l * 2 * D_, enc_ln_b + (size_t)l * 2 * D_, MS);

        // FFN, chunked by 8192 rows (mid aliases dead qkv region)
        for (int m0 = 0; m0 < MS; m0 += 8192) {
            gemm(h + (size_t)m0 * D_, D_, wsc + 4 * WDD,
                 enc_ffn_b1 + (size_t)l * F_, mid, F_, 8192, F_, D_, 1);
            gemm(mid, F_, wsc + 4 * WDD + WDF, enc_ffn_b2 + (size_t)l * D_,
                 o + (size_t)m0 * D_, D_, 8192, D_, F_, 0);
        }
        addln(h, o, enc_ln_s + (size_t)l * 2 * D_ + D_,
              enc_ln_b + (size_t)l * 2 * D_ + D_, MS);
    }
    // h == memory from here on.

    // ---- decoder ----
    embed_tgt_kernel<<<dim3((B_ * T_ * D_ + 255) / 256), dim3(256), 0, stream>>>(
        y, tgt_w, tgt_b, dbuf);
    for (int l = 0; l < L_; ++l) {
        wconv(dec_self_w  + (size_t)l * 4 * WDD, wsc, D_, D_, 4);
        wconv(dec_cross_w + (size_t)l * 4 * WDD, wsc + 4 * WDD, D_, D_, 4);
        wconv(dec_ffn_w1  + (size_t)l * WDF, wsc + 8 * WDD, D_, F_, 1);
        wconv(dec_ffn_w2  + (size_t)l * WDF, wsc + 8 * WDD + WDF, F_, D_, 1);

        // self-attention (causal), fused QKV
        const float* bl = dec_self_b + (size_t)l * 4 * D_;
        gemm(dbuf, D_, wsc, bl, qkv, 1536, MT, 1536, D_, 0);
        attn(qkv, 1536, qkv + 512, 1536, qkv + 1024, qkv, T_, T_, 1);
        gemm(qkv, 1536, wsc + 3 * WDD, bl + 3 * D_, o, D_, MT, D_, D_, 0);
        addln(dbuf, o, dec_ln_s + (size_t)l * 3 * D_,
              dec_ln_b + (size_t)l * 3 * D_, MT);

        // cross-attention: fused KV over memory, Q over decoder state
        const float* bc = dec_cross_b + (size_t)l * 4 * D_;
        gemm(h, D_, wsc + 5 * WDD, bc + D_, ckv, 1024, MS, 1024, D_, 0);
        gemm(dbuf, D_, wsc + 4 * WDD, bc, cq, D_, MT, D_, D_, 0);
        attn(cq, 512, ckv, 1024, ckv + 512, cq, T_, S_, 0);   // in-place
        gemm(cq, D_, wsc + 7 * WDD, bc + 3 * D_, o, D_, MT, D_, D_, 0);
        addln(dbuf, o, dec_ln_s + (size_t)l * 3 * D_ + D_,
              dec_ln_b + (size_t)l * 3 * D_ + D_, MT);

        // FFN (single chunk, MT=5760 rows)
        gemm(dbuf, D_, wsc + 8 * WDD, dec_ffn_b1 + (size_t)l * F_,
             mid, F_, MT, F_, D_, 1);
        gemm(mid, F_, wsc + 8 * WDD + WDF, dec_ffn_b2 + (size_t)l * D_,
             o, D_, MT, D_, F_, 0);
        addln(dbuf, o, dec_ln_s + (size_t)l * 3 * D_ + 2 * D_,
              dec_ln_b + (size_t)l * 3 * D_ + 2 * D_, MT);
    }

    out_proj_kernel<<<dim3(MT), dim3(64), 0, stream>>>(dbuf, out_w, out_b, out);
}

// Round 6
// 3495.014 us; speedup vs baseline: 7.0044x; 1.0785x over previous
//
#include <hip/hip_runtime.h>
#include <math.h>

// Problem constants (TransformerController)
#define B_  32
#define S_  512
#define T_  180
#define D_  512
#define F_  2048
#define L_  6
#define H_  8
#define DH_ 64

typedef unsigned short u16;
typedef __attribute__((ext_vector_type(8))) short short8;   // 8 x bf16
typedef __attribute__((ext_vector_type(4))) float floatx4;  // MFMA acc

__device__ __forceinline__ float bf2f(u16 h) {
    union { unsigned u; float f; } un; un.u = ((unsigned)h) << 16; return un.f;
}
__device__ __forceinline__ u16 f2bf(float f) {
    union { float f; unsigned u; } un; un.f = f;
    unsigned u = un.u;
    u += 0x7fffu + ((u >> 16) & 1u);   // RNE
    return (u16)(u >> 16);
}

// async global->LDS, 16B per lane, dest = wave-uniform base + lane*16
__device__ __forceinline__ void gload16(const u16* g, u16* l) {
    __builtin_amdgcn_global_load_lds(
        (const __attribute__((address_space(1))) void*)g,
        (__attribute__((address_space(3))) void*)l, 16, 0, 0);
}

// ---------------------------------------------------------------------------
// Embedding kernels -> bf16
// ---------------------------------------------------------------------------
__device__ __forceinline__ float pos_enc(int pos, int c) {
    int i2 = c & ~1;
    float div = expf(-(float)i2 * (9.210340371976184f / 512.0f));
    float arg = (float)pos * div;
    return (c & 1) ? cosf(arg) : sinf(arg);
}

__global__ __launch_bounds__(256) void embed_src_kernel(
    const float* __restrict__ x, const float* __restrict__ w,
    const float* __restrict__ b, u16* __restrict__ h)
{
    int idx = blockIdx.x * 256 + threadIdx.x;
    if (idx >= B_ * S_ * D_) return;
    int c  = idx & (D_ - 1);
    int bs = idx >> 9;
    int s  = bs & (S_ - 1);
    float x0 = x[bs * 2 + 0];
    float x1 = x[bs * 2 + 1];
    h[idx] = f2bf(x0 * w[c] + x1 * w[D_ + c] + b[c] + pos_enc(s, c));
}

__global__ __launch_bounds__(256) void embed_tgt_kernel(
    const float* __restrict__ y, const float* __restrict__ w,
    const float* __restrict__ b, u16* __restrict__ d)
{
    int idx = blockIdx.x * 256 + threadIdx.x;
    if (idx >= B_ * T_ * D_) return;
    int c  = idx & (D_ - 1);
    int bt = idx >> 9;
    int t  = bt % T_;
    int bb = bt / T_;
    float tv = (t == 0) ? 0.0f : y[bb * T_ + (t - 1)];
    d[idx] = f2bf(tv * w[c] + b[c] + pos_enc(t, c));
}

// ---------------------------------------------------------------------------
// Weight convert+transpose: W[K,N] fp32 -> Wt[N,K] bf16. blockIdx.z = matrix.
// ---------------------------------------------------------------------------
__global__ __launch_bounds__(256) void wconv_kernel(
    const float* __restrict__ W, u16* __restrict__ Wt, int K, int N)
{
    __shared__ float tile[32][33];
    size_t mat = (size_t)blockIdx.z * K * N;
    const float* Wm = W + mat;
    u16* Wtm = Wt + mat;
    int n0 = blockIdx.x * 32, k0 = blockIdx.y * 32;
    int tx = threadIdx.x & 31, ty = threadIdx.x >> 5;   // ty 0..7
#pragma unroll
    for (int i = 0; i < 32; i += 8)
        tile[ty + i][tx] = Wm[(size_t)(k0 + ty + i) * N + n0 + tx];
    __syncthreads();
#pragma unroll
    for (int i = 0; i < 32; i += 8)
        Wtm[(size_t)(n0 + ty + i) * K + k0 + tx] = f2bf(tile[tx][ty + i]);
}

// ---------------------------------------------------------------------------
// bf16 MFMA GEMM: C[M,N] = act(A[M,K](lda) @ Wt[N,K]^T + bias), bf16 io,
// fp32 acc. 128x128 tile, BK=64 (two 32-halves per barrier pair), 256 thr
// (4 waves, 2x2 of 64x64 quadrants). M,N mult of 128; K mult of 64.
// ---------------------------------------------------------------------------
__global__ __launch_bounds__(256) void gemm_bf16_kernel(
    const u16* __restrict__ A, int lda, const u16* __restrict__ Bt,
    const float* __restrict__ bias, u16* __restrict__ C, int ldc,
    int M, int N, int K, int relu)
{
    // As/Bs: 2 halves x (128 rows x 32 k) = 8192 u16 each. epi aliases all.
    __shared__ u16 smem[18432];
    u16* As = smem;            // halves at 0, 4096
    u16* Bs = smem + 8192;     // halves at 8192, 12288

    int tid  = threadIdx.x;
    int w    = tid >> 6;
    int lane = tid & 63;
    int m0 = blockIdx.y << 7, n0 = blockIdx.x << 7;

    // staging: per half, per wave 2 instrs A + 2 instrs B; 16 rows/instr
    int sr = w * 32 + (lane >> 2);
    int sk = (lane & 3) * 8;
    const u16* ag0 = A  + (size_t)(m0 + sr)      * lda + sk;
    const u16* ag1 = A  + (size_t)(m0 + sr + 16) * lda + sk;
    const u16* bg0 = Bt + (size_t)(n0 + sr)      * K + sk;
    const u16* bg1 = Bt + (size_t)(n0 + sr + 16) * K + sk;
    u16* al0 = As + (w * 2 + 0) * 512;
    u16* al1 = As + (w * 2 + 1) * 512;
    u16* bl0 = Bs + (w * 2 + 0) * 512;
    u16* bl1 = Bs + (w * 2 + 1) * 512;

    int wm = (w >> 1) * 64, wn = (w & 1) * 64;
    int fr = lane & 15;
    int fk = (lane >> 4) * 8;

    floatx4 acc[4][4] = {};

    for (int k0 = 0; k0 < K; k0 += 64) {
#pragma unroll
        for (int hh = 0; hh < 2; ++hh) {
            int go = k0 + hh * 32;
            int lo = hh * 4096;
            gload16(ag0 + go, al0 + lo);
            gload16(ag1 + go, al1 + lo);
            gload16(bg0 + go, bl0 + lo);
            gload16(bg1 + go, bl1 + lo);
        }
        __syncthreads();

#pragma unroll
        for (int hh = 0; hh < 2; ++hh) {
            int lo = hh * 4096;
            short8 af[4], bf[4];
#pragma unroll
            for (int i = 0; i < 4; ++i)
                af[i] = *(const short8*)&As[lo + (wm + i * 16 + fr) * 32 + fk];
#pragma unroll
            for (int j = 0; j < 4; ++j)
                bf[j] = *(const short8*)&Bs[lo + (wn + j * 16 + fr) * 32 + fk];
#pragma unroll
            for (int i = 0; i < 4; ++i)
#pragma unroll
                for (int j = 0; j < 4; ++j)
                    acc[i][j] = __builtin_amdgcn_mfma_f32_16x16x32_bf16(
                        af[i], bf[j], acc[i][j], 0, 0, 0);
        }
        __syncthreads();
    }

    // epilogue: bias+relu+bf16, bounce through LDS for coalesced stores.
    // C/D frag layout: col=lane&15, row=(lane>>4)*4+reg
    u16* epi = smem + w * 4608;        // 64 rows x 72 u16 stride
    int cc = lane & 15;
    int rq = (lane >> 4) * 4;
#pragma unroll
    for (int j = 0; j < 4; ++j) {
        float bj = bias[n0 + wn + j * 16 + cc];
#pragma unroll
        for (int i = 0; i < 4; ++i) {
#pragma unroll
            for (int r = 0; r < 4; ++r) {
                float vv = acc[i][j][r] + bj;
                if (relu) vv = fmaxf(vv, 0.f);
                epi[(i * 16 + rq + r) * 72 + j * 16 + cc] = f2bf(vv);
            }
        }
    }
    __syncthreads();
#pragma unroll
    for (int t = 0; t < 8; ++t) {
        int er = t * 8 + (lane >> 3);
        int ec = (lane & 7) * 8;
        short8 vv = *(const short8*)&epi[er * 72 + ec];
        *(short8*)&C[(size_t)(m0 + wm + er) * ldc + n0 + wn + ec] = vv;
    }
}

// ---------------------------------------------------------------------------
// MFMA flash attention, bf16 io, fp32 softmax/acc. Strided (slices of fused
// QKV buffers), IN-PLACE capable (O aliases Q slice). Grid = (b*H, q-tile)
// so all q-tiles of one (b,h) share an XCD (L2 reuse of K/V).
// One block = 64 q-rows: 4 waves x 16 q. 64-key tiles. QK^T / PV on MFMA.
// Mask evaluated only on boundary/causal tiles. exp2-based online softmax
// with the 1/sqrt(DH) scale folded into the exponent.
// ---------------------------------------------------------------------------
#define CEXP 0.1803368801111244f   // 0.125 * log2(e)

__global__ __launch_bounds__(256) void attn_mfma_kernel(
    const u16* Q, int qs, const u16* __restrict__ K, int ks,
    const u16* __restrict__ V, u16* O,
    int Sq, int Sk, int causal)
{
    __shared__ u16 Qs[64 * 72];      // [qrow][d], stride 72
    __shared__ u16 Ks[64 * 72];      // [key][d]
    __shared__ u16 Vt[64 * 72];      // [d][(k + (d&~7)) & 63] (rotated cols)
    __shared__ u16 Ps[4][16 * 72];   // per-wave P tile [q][key]

    int tid  = threadIdx.x;
    int w    = tid >> 6;
    int lane = tid & 63;
    int n    = lane & 15;
    int quad = lane >> 4;
    int bh = blockIdx.x;
    int bb = bh >> 3, hhd = bh & 7;
    int q0 = blockIdx.y * 64;

    const u16* Qb = Q + (size_t)bb * Sq * qs + hhd * DH_;
    const u16* Kb = K + (size_t)bb * Sk * ks + hhd * DH_;
    const u16* Vb = V + (size_t)bb * Sk * ks + hhd * DH_;

    // ---- stage Q once: 64 rows x 64 d ----
#pragma unroll
    for (int it = 0; it < 2; ++it) {
        int idx = it * 256 + tid;          // 0..511
        int r = idx >> 3, dg = (idx & 7) * 8;
        int qg = q0 + r;
        short8 vv = {};
        if (qg < Sq) vv = *(const short8*)&Qb[(size_t)qg * qs + dg];
        *(short8*)&Qs[r * 72 + dg] = vv;
    }

    float m_i[4], l_i[4];
    floatx4 o_acc[4] = {};
#pragma unroll
    for (int r = 0; r < 4; ++r) { m_i[r] = -1e30f; l_i[r] = 0.f; }

    int qrow0 = q0 + w * 16 + quad * 4;    // this lane's 4 q-rows
    int kend = causal ? ((Sk < q0 + 64) ? Sk : (q0 + 64)) : Sk;
    __syncthreads();

    for (int k0 = 0; k0 < kend; k0 += 64) {
        // ---- stage K (row-major) and V (transposed, rotated cols) ----
#pragma unroll
        for (int it = 0; it < 2; ++it) {
            int idx = it * 256 + tid;
            int r = idx >> 3, dg = (idx & 7) * 8;
            int kg = k0 + r;
            short8 kv = {}, vv = {};
            if (kg < Sk) {
                kv = *(const short8*)&Kb[(size_t)kg * ks + dg];
                vv = *(const short8*)&Vb[(size_t)kg * ks + dg];
            }
            *(short8*)&Ks[r * 72 + dg] = kv;
            int col = (r + dg) & 63;       // rotation by dg = d & ~7
#pragma unroll
            for (int j = 0; j < 8; ++j)
                Vt[(dg + j) * 72 + col] = (u16)vv[j];
        }
        __syncthreads();

        // ---- QK^T: S-tile 16q x 64k in C-layout frags (raw scores) ----
        floatx4 sc[4] = {};
        short8 aq0 = *(const short8*)&Qs[(w * 16 + n) * 72 + quad * 8];
        short8 aq1 = *(const short8*)&Qs[(w * 16 + n) * 72 + 32 + quad * 8];
#pragma unroll
        for (int j = 0; j < 4; ++j) {
            short8 bk0 = *(const short8*)&Ks[(j * 16 + n) * 72 + quad * 8];
            short8 bk1 = *(const short8*)&Ks[(j * 16 + n) * 72 + 32 + quad * 8];
            sc[j] = __builtin_amdgcn_mfma_f32_16x16x32_bf16(aq0, bk0, sc[j], 0, 0, 0);
            sc[j] = __builtin_amdgcn_mfma_f32_16x16x32_bf16(aq1, bk1, sc[j], 0, 0, 0);
        }

        // ---- mask only when this wave's tile touches a boundary ----
        bool need_mask = (k0 + 64 > Sk) ||
                         (causal && (k0 + 63 > q0 + w * 16));
        if (need_mask) {
#pragma unroll
            for (int j = 0; j < 4; ++j) {
                int kg = k0 + j * 16 + n;
#pragma unroll
                for (int r = 0; r < 4; ++r) {
                    if (kg >= Sk || (causal && kg > qrow0 + r))
                        sc[j][r] = -1e30f;
                }
            }
        }

        // ---- online softmax: p = exp2((s - m) * CEXP), width-16 shfl ----
#pragma unroll
        for (int r = 0; r < 4; ++r) {
            float mx = fmaxf(fmaxf(sc[0][r], sc[1][r]), fmaxf(sc[2][r], sc[3][r]));
#pragma unroll
            for (int off = 8; off > 0; off >>= 1)
                mx = fmaxf(mx, __shfl_xor(mx, off, 16));
            float mnew = fmaxf(m_i[r], mx);
            float alpha = exp2f((m_i[r] - mnew) * CEXP);
            m_i[r] = mnew;
            float ps = 0.f;
#pragma unroll
            for (int j = 0; j < 4; ++j) {
                float p = exp2f((sc[j][r] - mnew) * CEXP);
                sc[j][r] = p; ps += p;
            }
#pragma unroll
            for (int off = 8; off > 0; off >>= 1)
                ps += __shfl_xor(ps, off, 16);
            l_i[r] = l_i[r] * alpha + ps;
#pragma unroll
            for (int jb = 0; jb < 4; ++jb) o_acc[jb][r] *= alpha;
        }

        // ---- P: C-layout regs -> per-wave LDS [q][key] ----
#pragma unroll
        for (int j = 0; j < 4; ++j)
#pragma unroll
            for (int r = 0; r < 4; ++r)
                Ps[w][(quad * 4 + r) * 72 + j * 16 + n] = f2bf(sc[j][r]);

        // ---- PV: A = P (LDS, A-layout), B = V^T (rotated) ----
        short8 ap0 = *(const short8*)&Ps[w][n * 72 + quad * 8];
        short8 ap1 = *(const short8*)&Ps[w][n * 72 + 32 + quad * 8];
#pragma unroll
        for (int jb = 0; jb < 4; ++jb) {
            int d = jb * 16 + n;
            int rot = d & ~7;
            short8 bv0 = *(const short8*)&Vt[d * 72 + ((quad * 8 + rot) & 63)];
            short8 bv1 = *(const short8*)&Vt[d * 72 + ((32 + quad * 8 + rot) & 63)];
            o_acc[jb] = __builtin_amdgcn_mfma_f32_16x16x32_bf16(ap0, bv0, o_acc[jb], 0, 0, 0);
            o_acc[jb] = __builtin_amdgcn_mfma_f32_16x16x32_bf16(ap1, bv1, o_acc[jb], 0, 0, 0);
        }
        __syncthreads();
    }

    // ---- output: O[q][d], C-layout frags ----
    float inv[4];
#pragma unroll
    for (int r = 0; r < 4; ++r) inv[r] = 1.0f / l_i[r];
    u16* Ob = O + (size_t)bb * Sq * qs + hhd * DH_;
#pragma unroll
    for (int r = 0; r < 4; ++r) {
        int qg = qrow0 + r;
        if (qg < Sq) {
#pragma unroll
            for (int jb = 0; jb < 4; ++jb)
                Ob[(size_t)qg * qs + jb * 16 + n] = f2bf(o_acc[jb][r] * inv[r]);
        }
    }
}

// ---------------------------------------------------------------------------
// h[row,:] = LN(h[row,:] + delta[row,:]) * scale + bias (bf16 io, fp32 math)
// 128 threads, single barrier (wave shfl reduction, E[x^2]-mu^2 variance).
// ---------------------------------------------------------------------------
__global__ __launch_bounds__(128) void add_ln_kernel(
    u16* __restrict__ h, const u16* __restrict__ delta,
    const float* __restrict__ scale, const float* __restrict__ bias)
{
    __shared__ float red[2][2];
    int row = blockIdx.x, tid = threadIdx.x;
    int lane = tid & 63, wv = tid >> 6;
    size_t base = (size_t)row * D_ + tid * 4;
    uint2 hv = *(const uint2*)&h[base];
    uint2 dv = *(const uint2*)&delta[base];
    float v0 = bf2f(hv.x & 0xffff) + bf2f(dv.x & 0xffff);
    float v1 = bf2f(hv.x >> 16)    + bf2f(dv.x >> 16);
    float v2 = bf2f(hv.y & 0xffff) + bf2f(dv.y & 0xffff);
    float v3 = bf2f(hv.y >> 16)    + bf2f(dv.y >> 16);

    float a  = v0 + v1 + v2 + v3;
    float b2 = v0 * v0 + v1 * v1 + v2 * v2 + v3 * v3;
#pragma unroll
    for (int off = 32; off > 0; off >>= 1) {
        a  += __shfl_xor(a, off);
        b2 += __shfl_xor(b2, off);
    }
    if (lane == 0) { red[wv][0] = a; red[wv][1] = b2; }
    __syncthreads();
    float S1 = red[0][0] + red[1][0];
    float S2 = red[0][1] + red[1][1];
    float mu = S1 * (1.0f / 512.0f);
    float var = S2 * (1.0f / 512.0f) - mu * mu;
    float rs = rsqrtf(var + 1e-5f);

    int c = tid * 4;
    float4 sc = *(const float4*)&scale[c];
    float4 bi = *(const float4*)&bias[c];
    unsigned lo = (unsigned)f2bf((v0 - mu) * rs * sc.x + bi.x) |
                  ((unsigned)f2bf((v1 - mu) * rs * sc.y + bi.y) << 16);
    unsigned hi = (unsigned)f2bf((v2 - mu) * rs * sc.z + bi.z) |
                  ((unsigned)f2bf((v3 - mu) * rs * sc.w + bi.w) << 16);
    *(uint2*)&h[base] = make_uint2(lo, hi);
}

// ---------------------------------------------------------------------------
// out[row] = d[row,:] . w[:] + b   (one wave per row; d bf16, out fp32)
// ---------------------------------------------------------------------------
__global__ __launch_bounds__(64) void out_proj_kernel(
    const u16* __restrict__ d, const float* __restrict__ w,
    const float* __restrict__ b, float* __restrict__ out)
{
    int row = blockIdx.x, lane = threadIdx.x;
    float s = 0.f;
    for (int c = lane; c < D_; c += 64) s += bf2f(d[(size_t)row * D_ + c]) * w[c];
#pragma unroll
    for (int off = 32; off > 0; off >>= 1) s += __shfl_down(s, off);
    if (lane == 0) out[row] = s + b[0];
}

// ---------------------------------------------------------------------------
// Host orchestration
// ---------------------------------------------------------------------------
extern "C" void kernel_launch(void* const* d_in, const int* in_sizes, int n_in,
                              void* d_out, int out_size, void* d_ws, size_t ws_size,
                              hipStream_t stream)
{
    const float* x          = (const float*)d_in[0];
    const float* y          = (const float*)d_in[1];
    const float* src_w      = (const float*)d_in[2];
    const float* src_b      = (const float*)d_in[3];
    const float* tgt_w      = (const float*)d_in[4];
    const float* tgt_b      = (const float*)d_in[5];
    const float* enc_attn_w = (const float*)d_in[6];
    const float* enc_attn_b = (const float*)d_in[7];
    const float* enc_ffn_w1 = (const float*)d_in[8];
    const float* enc_ffn_b1 = (const float*)d_in[9];
    const float* enc_ffn_w2 = (const float*)d_in[10];
    const float* enc_ffn_b2 = (const float*)d_in[11];
    const float* enc_ln_s   = (const float*)d_in[12];
    const float* enc_ln_b   = (const float*)d_in[13];
    const float* dec_self_w = (const float*)d_in[14];
    const float* dec_self_b = (const float*)d_in[15];
    const float* dec_cross_w= (const float*)d_in[16];
    const float* dec_cross_b= (const float*)d_in[17];
    const float* dec_ffn_w1 = (const float*)d_in[18];
    const float* dec_ffn_b1 = (const float*)d_in[19];
    const float* dec_ffn_w2 = (const float*)d_in[20];
    const float* dec_ffn_b2 = (const float*)d_in[21];
    const float* dec_ln_s   = (const float*)d_in[22];
    const float* dec_ln_b   = (const float*)d_in[23];
    const float* out_w      = (const float*)d_in[24];
    const float* out_b      = (const float*)d_in[25];
    float* out = (float*)d_out;

    // Workspace (u16 elems). Total = 49,086,464 u16 = 98.2 MB.
    const size_t E_BSD = (size_t)B_ * S_ * D_;    // 8,388,608
    const size_t E_BTD = (size_t)B_ * T_ * D_;    // 2,949,120
    const size_t WDD   = (size_t)D_ * D_;         // 262,144
    const size_t WDF   = (size_t)D_ * F_;         // 1,048,576
    const int MS = B_ * S_;   // 16384
    const int MT = B_ * T_;   // 5760

    u16* h    = (u16*)d_ws;                  // encoder state -> memory
    u16* qkv  = h + E_BSD;                   // [MS,1536] fused QKV / scratch
    u16* o    = qkv + (size_t)MS * 1536;     // [MS,512] proj/FFN output
    u16* dbuf = o + E_BSD;                   // decoder state
    u16* wsc  = dbuf + E_BTD;                // weight scratch (10 slots max)
    // aliases into qkv region (dead when used):
    u16* mid  = qkv;                         // FFN hidden (<= 8192x2048)
    u16* cq   = qkv;                         // cross-attn Q [MT,512]
    u16* ckv  = qkv + 4 * 1024 * 1024;       // cross-attn KV [MS,1024]

    auto gemm = [&](const u16* A, int lda, const u16* Wt, const float* bi,
                    u16* C, int ldc, int M, int N, int K, int relu) {
        dim3 g(N / 128, M / 128);
        gemm_bf16_kernel<<<g, dim3(256), 0, stream>>>(A, lda, Wt, bi, C, ldc,
                                                      M, N, K, relu);
    };
    auto attn = [&](const u16* Qp, int qs, const u16* Kp, int ks,
                    const u16* Vp, u16* Op, int Sq, int Sk, int causal) {
        dim3 g(B_ * H_, (Sq + 63) / 64);
        attn_mfma_kernel<<<g, dim3(256), 0, stream>>>(Qp, qs, Kp, ks, Vp, Op,
                                                      Sq, Sk, causal);
    };
    auto addln = [&](u16* hp, const u16* dp, const float* sc, const float* bi,
                     int rows) {
        add_ln_kernel<<<dim3(rows), dim3(128), 0, stream>>>(hp, dp, sc, bi);
    };
    auto wconv = [&](const float* W, u16* Wt, int K, int N, int nmat) {
        wconv_kernel<<<dim3(N / 32, K / 32, nmat), dim3(256), 0, stream>>>(W, Wt, K, N);
    };

    // ---- encoder ----
    embed_src_kernel<<<dim3((B_ * S_ * D_ + 255) / 256), dim3(256), 0, stream>>>(
        x, src_w, src_b, h);
    for (int l = 0; l < L_; ++l) {
        wconv(enc_attn_w + (size_t)l * 4 * WDD, wsc, D_, D_, 4);   // q,k,v,o
        wconv(enc_ffn_w1 + (size_t)l * WDF, wsc + 4 * WDD, D_, F_, 1);
        wconv(enc_ffn_w2 + (size_t)l * WDF, wsc + 4 * WDD + WDF, F_, D_, 1);

        const float* bl = enc_attn_b + (size_t)l * 4 * D_;
        // fused QKV: N=1536, bias [bq|bk|bv] contiguous
        gemm(h, D_, wsc, bl, qkv, 1536, MS, 1536, D_, 0);
        attn(qkv, 1536, qkv + 512, 1536, qkv + 1024, qkv, S_, S_, 0); // in-place
        gemm(qkv, 1536, wsc + 3 * WDD, bl + 3 * D_, o, D_, MS, D_, D_, 0);
        addln(h, o, enc_ln_s + (size_t)l * 2 * D_, enc_ln_b + (size_t)l * 2 * D_, MS);

        // FFN, chunked by 8192 rows (mid aliases dead qkv region)
        for (int m0 = 0; m0 < MS; m0 += 8192) {
            gemm(h + (size_t)m0 * D_, D_, wsc + 4 * WDD,
                 enc_ffn_b1 + (size_t)l * F_, mid, F_, 8192, F_, D_, 1);
            gemm(mid, F_, wsc + 4 * WDD + WDF, enc_ffn_b2 + (size_t)l * D_,
                 o + (size_t)m0 * D_, D_, 8192, D_, F_, 0);
        }
        addln(h, o, enc_ln_s + (size_t)l * 2 * D_ + D_,
              enc_ln_b + (size_t)l * 2 * D_ + D_, MS);
    }
    // h == memory from here on.

    // ---- decoder ----
    embed_tgt_kernel<<<dim3((B_ * T_ * D_ + 255) / 256), dim3(256), 0, stream>>>(
        y, tgt_w, tgt_b, dbuf);
    for (int l = 0; l < L_; ++l) {
        wconv(dec_self_w  + (size_t)l * 4 * WDD, wsc, D_, D_, 4);
        wconv(dec_cross_w + (size_t)l * 4 * WDD, wsc + 4 * WDD, D_, D_, 4);
        wconv(dec_ffn_w1  + (size_t)l * WDF, wsc + 8 * WDD, D_, F_, 1);
        wconv(dec_ffn_w2  + (size_t)l * WDF, wsc + 8 * WDD + WDF, F_, D_, 1);

        // self-attention (causal), fused QKV
        const float* bl = dec_self_b + (size_t)l * 4 * D_;
        gemm(dbuf, D_, wsc, bl, qkv, 1536, MT, 1536, D_, 0);
        attn(qkv, 1536, qkv + 512, 1536, qkv + 1024, qkv, T_, T_, 1);
        gemm(qkv, 1536, wsc + 3 * WDD, bl + 3 * D_, o, D_, MT, D_, D_, 0);
        addln(dbuf, o, dec_ln_s + (size_t)l * 3 * D_,
              dec_ln_b + (size_t)l * 3 * D_, MT);

        // cross-attention: fused KV over memory, Q over decoder state
        const float* bc = dec_cross_b + (size_t)l * 4 * D_;
        gemm(h, D_, wsc + 5 * WDD, bc + D_, ckv, 1024, MS, 1024, D_, 0);
        gemm(dbuf, D_, wsc + 4 * WDD, bc, cq, D_, MT, D_, D_, 0);
        attn(cq, 512, ckv, 1024, ckv + 512, cq, T_, S_, 0);   // in-place
        gemm(cq, D_, wsc + 7 * WDD, bc + 3 * D_, o, D_, MT, D_, D_, 0);
        addln(dbuf, o, dec_ln_s + (size_t)l * 3 * D_ + D_,
              dec_ln_b + (size_t)l * 3 * D_ + D_, MT);

        // FFN (single chunk, MT=5760 rows)
        gemm(dbuf, D_, wsc + 8 * WDD, dec_ffn_b1 + (size_t)l * F_,
             mid, F_, MT, F_, D_, 1);
        gemm(mid, F_, wsc + 8 * WDD + WDF, dec_ffn_b2 + (size_t)l * D_,
             o, D_, MT, D_, F_, 0);
        addln(dbuf, o, dec_ln_s + (size_t)l * 3 * D_ + 2 * D_,
              dec_ln_b + (size_t)l * 3 * D_ + 2 * D_, MT);
    }

    out_proj_kernel<<<dim3(MT), dim3(64), 0, stream>>>(dbuf, out_w, out_b, out);
}